// Round 1
// baseline (543.525 us; speedup 1.0000x reference)
//
#include <hip/hip_runtime.h>
#include <hip/hip_bf16.h>
#include <math.h>

typedef __bf16 bf16;
typedef bf16 bf16x8 __attribute__((ext_vector_type(8)));
typedef bf16 bf16x4 __attribute__((ext_vector_type(4)));
typedef float f32x4 __attribute__((ext_vector_type(4)));

#define ROWS 8192      // B*S = 4*2048
#define EMB  1024
#define NH_  16
#define HD   64
#define FFN  4096
#define QKVN 3072
#define SEQ  2048

// async global->LDS, 16B per lane; LDS dest is wave-uniform base + lane*16
__device__ __forceinline__ void gl2lds16(const bf16* g, bf16* l) {
  __builtin_amdgcn_global_load_lds((const __attribute__((address_space(1))) void*)g,
                                   (__attribute__((address_space(3))) void*)l, 16, 0, 0);
}

// ---------------------------------------------------------------------------
// Transpose-cast: W [K][N] fp32 -> Wt [N][K] bf16 (times scale).
// grid (N/32, K/32), 256 thr.
// ---------------------------------------------------------------------------
__global__ void transpose_cast(const float* __restrict__ W, bf16* __restrict__ Wt,
                               int K, int N, float scale) {
  __shared__ float tile[32][33];
  const int n0 = blockIdx.x * 32, k0 = blockIdx.y * 32;
  const int tx = threadIdx.x & 31, ty = threadIdx.x >> 5;  // ty 0..7
#pragma unroll
  for (int i = 0; i < 32; i += 8)
    tile[ty + i][tx] = W[(size_t)(k0 + ty + i) * N + n0 + tx];
  __syncthreads();
#pragma unroll
  for (int i = 0; i < 32; i += 8)
    Wt[(size_t)(n0 + ty + i) * K + k0 + tx] = (bf16)(tile[tx][ty + i] * scale);
}

// ---------------------------------------------------------------------------
// V transpose: qkv V-part [b*2048+s][2048 + h*64 + d] -> vt[(bh*64+d)*2048+s]
// ---------------------------------------------------------------------------
__global__ void v_transpose(const bf16* __restrict__ qkv, bf16* __restrict__ vt) {
  __shared__ bf16 tile[32][33];
  const int s0 = blockIdx.x * 32, d0 = blockIdx.y * 32, bh = blockIdx.z;
  const int b = bh >> 4, h = bh & 15;
  const int tx = threadIdx.x & 31, ty = threadIdx.x >> 5;
#pragma unroll
  for (int i = 0; i < 32; i += 8)
    tile[ty + i][tx] = qkv[(size_t)(b * SEQ + s0 + ty + i) * QKVN + 2 * EMB + h * HD + d0 + tx];
  __syncthreads();
#pragma unroll
  for (int i = 0; i < 32; i += 8)
    vt[(size_t)(bh * HD + d0 + ty + i) * SEQ + s0 + tx] = tile[tx][ty + i];
}

// ---------------------------------------------------------------------------
// LayerNorm fp32 -> bf16.  One block (256 thr) per row of 1024.
// ---------------------------------------------------------------------------
__global__ void layernorm_bf16(const float* __restrict__ x, const float* __restrict__ g,
                               const float* __restrict__ b, bf16* __restrict__ out) {
  const int row = blockIdx.x;
  const int t = threadIdx.x;
  const float4 v = ((const float4*)(x + (size_t)row * EMB))[t];
  float s = v.x + v.y + v.z + v.w;
  float ss = v.x * v.x + v.y * v.y + v.z * v.z + v.w * v.w;
#pragma unroll
  for (int off = 32; off; off >>= 1) {
    s += __shfl_down(s, off);
    ss += __shfl_down(ss, off);
  }
  __shared__ float sbuf[8];
  const int wave = t >> 6, lane = t & 63;
  if (lane == 0) { sbuf[wave] = s; sbuf[4 + wave] = ss; }
  __syncthreads();
  if (t == 0) {
    float S = sbuf[0] + sbuf[1] + sbuf[2] + sbuf[3];
    float SS = sbuf[4] + sbuf[5] + sbuf[6] + sbuf[7];
    float mu = S * (1.0f / EMB);
    float var = SS * (1.0f / EMB) - mu * mu;
    sbuf[0] = mu;
    sbuf[1] = rsqrtf(var + 1e-5f);
  }
  __syncthreads();
  const float mu = sbuf[0], rs = sbuf[1];
  const float4 gv = ((const float4*)g)[t];
  const float4 bv = ((const float4*)b)[t];
  bf16x4 o;
  o[0] = (bf16)((v.x - mu) * rs * gv.x + bv.x);
  o[1] = (bf16)((v.y - mu) * rs * gv.y + bv.y);
  o[2] = (bf16)((v.z - mu) * rs * gv.z + bv.z);
  o[3] = (bf16)((v.w - mu) * rs * gv.w + bv.w);
  *(bf16x4*)(out + (size_t)row * EMB + t * 4) = o;
}

// ---------------------------------------------------------------------------
// 8-phase 256-wide GEMM (HK-style schedule in plain HIP, per guide §5):
//   C[M=8192][N] = A[M][K](bf16 rm) * Bt[N][K]^T, BM=256, BK=64, 512 thr
//   (8 waves, 2M x 4N), BN in {256,128}.  LDS XOR-swizzle (chunk c of row r
//   at c^(r&7)); raw s_barrier (NOT __syncthreads) + counted vmcnt so the
//   global_load_lds queue pipelines ACROSS barriers (never drained to 0 in
//   the main loop).  Per K-tile: 4 phases, each {ds_read subtile | stage one
//   half-tile | barrier | lgkmcnt(0) | setprio(1) MFMA setprio(0) | barrier}.
//   Stage stream per tile t: [A1(t+1), B0(t+2), B1(t+2), A0(t+2)] -- every
//   stage targets a region whose last LDS read completed >=1 barrier earlier
//   (B read only in ph1; A-low ph1; A-high ph3).  Steady vmcnt leaves
//   {B0,B1,A0}(t+2) in flight.
// Epilogues: 0=bf16  1=+resid f32  2=+bias,GELU(tanh) bf16  3=+bias+resid f32
// ---------------------------------------------------------------------------
template <int EPI, int N_, int K_, int BN_>
__global__ __launch_bounds__(512, 2) void gemm8p(
    const bf16* __restrict__ A, const bf16* __restrict__ Bt, void* __restrict__ C,
    const float* __restrict__ bias, const float* __restrict__ resid) {
  constexpr int K = K_;
  constexpr int NF = BN_ / 64;        // B frags per wave (4 or 2)
  constexpr int NHF = NF / 2;         // frags per N-half (2 or 1)
  constexpr int WTN = BN_ / 4;        // per-wave N extent (64 or 32)
  constexpr int BRH = BN_ / 2;        // B staging-half rows (128 or 64)
  constexpr int BCALLS = BRH / 64;    // gl2lds calls per B half (2 or 1)
  constexpr int VM_N = 2 * BCALLS + 2;  // steady-state counted vmcnt
  constexpr int MT = ROWS / 256;
  constexpr int NT = N_ / BN_;
  constexpr int NTK = K / 64;
  static_assert((MT * NT) % 8 == 0, "grid must split evenly over 8 XCDs");
  static_assert(NTK >= 4 && (NTK % 2) == 0, "K-tile count must be even >=4");

  __shared__ __align__(16) bf16 As[2][256 * 64];   // 64 KB
  __shared__ __align__(16) bf16 Bs[2][BN_ * 64];   // 64/32 KB

  const int tid = threadIdx.x;
  const int lane = tid & 63, wave = tid >> 6;
  const int wm = wave >> 2, wn = wave & 3;         // 2M x 4N wave grid
  const int quad = lane >> 4, l16 = lane & 15;
  const int srow = lane >> 3, ch = lane & 7;       // staging row/chunk in 8x8
  const int xr = l16 & 7;                          // read-side XOR key

  // bijective XCD swizzle: consecutive wgids in an XCD share the B panel
  constexpr int nwg = MT * NT;
  constexpr int cpx = nwg / 8;
  const int lin = blockIdx.x;
  const int wgid = (lin & 7) * cpx + (lin >> 3);
  const int m0 = (wgid % MT) * 256;
  const int n0 = (wgid / MT) * BN_;

  // staging base pointers: pre-swizzled global column so linear LDS dest
  // yields chunk c of row r at position c^(r&7)  (both-sides rule #21)
  const bf16* a_src = A + (size_t)(m0 + wave * 8 + srow) * K + (ch ^ srow) * 8;
  const bf16* b_src = Bt + (size_t)(n0 + wave * 8 + srow) * K + (ch ^ srow) * 8;

  f32x4 acc[8][NF] = {};
  bf16x8 af[4][2];      // current A half-subtile (reloaded in ph3)
  bf16x8 bfr[NF][2];    // all B frags for this K-tile (loaded in ph1)

#define STAGE_A(BUF, HH, TT)                                                   \
  {                                                                            \
    _Pragma("unroll") for (int q = 0; q < 2; q++)                              \
        gl2lds16(a_src + (size_t)((HH)*128 + q * 64) * K + (size_t)(TT)*64,    \
                 &As[(BUF)][((HH)*128 + q * 64 + wave * 8) * 64]);             \
  }
#define STAGE_B(BUF, HH, TT)                                                   \
  {                                                                            \
    _Pragma("unroll") for (int q = 0; q < BCALLS; q++)                         \
        gl2lds16(b_src + (size_t)((HH)*BRH + q * 64) * K + (size_t)(TT)*64,    \
                 &Bs[(BUF)][((HH)*BRH + q * 64 + wave * 8) * 64]);             \
  }
#define DS_A(BUF, HH)                                                          \
  {                                                                            \
    _Pragma("unroll") for (int i = 0; i < 4; i++)                              \
        _Pragma("unroll") for (int ks = 0; ks < 2; ks++)                       \
            af[i][ks] = *(const bf16x8*)&As[(BUF)][                            \
                (wm * 128 + (HH)*64 + i * 16 + l16) * 64 +                     \
                (((ks * 4 + quad) ^ xr) * 8)];                                 \
  }
#define DS_B(BUF)                                                              \
  {                                                                            \
    _Pragma("unroll") for (int j = 0; j < NF; j++)                             \
        _Pragma("unroll") for (int ks = 0; ks < 2; ks++)                       \
            bfr[j][ks] = *(const bf16x8*)&Bs[(BUF)][                           \
                (wn * WTN + j * 16 + l16) * 64 +                               \
                (((ks * 4 + quad) ^ xr) * 8)];                                 \
  }
#define MMA_PH(IH, JH)                                                         \
  {                                                                            \
    _Pragma("unroll") for (int i = 0; i < 4; i++)                              \
        _Pragma("unroll") for (int jj = 0; jj < NHF; jj++)                     \
            _Pragma("unroll") for (int ks = 0; ks < 2; ks++)                   \
                acc[(IH)*4 + i][(JH)*NHF + jj] =                               \
                    __builtin_amdgcn_mfma_f32_16x16x32_bf16(                   \
                        af[i][ks], bfr[(JH)*NHF + jj][ks],                     \
                        acc[(IH)*4 + i][(JH)*NHF + jj], 0, 0, 0);              \
  }
// MODE: 0 = steady (full stage + vmcnt(VM_N)), 1 = t==NTK-2 (only A1(t+1),
// vmcnt(0)), 2 = last tile (no stages, no vmcnt)
#define KTILE(BUF, TT, MODE)                                                   \
  {                                                                            \
    /* phase 1: A-low + all B reads; stage A1(t+1) into other buffer */        \
    DS_A(BUF, 0);                                                              \
    DS_B(BUF);                                                                 \
    if ((MODE) < 2) STAGE_A((BUF) ^ 1, 1, (TT) + 1);                           \
    __builtin_amdgcn_s_barrier();                                              \
    asm volatile("s_waitcnt lgkmcnt(0)");                                      \
    __builtin_amdgcn_sched_barrier(0);                                         \
    __builtin_amdgcn_s_setprio(1);                                             \
    MMA_PH(0, 0);                                                              \
    __builtin_amdgcn_s_setprio(0);                                             \
    __builtin_amdgcn_s_barrier();                                              \
    /* phase 2: stage B0(t+2) (B region last read in ph1) */                   \
    if ((MODE) == 0) STAGE_B(BUF, 0, (TT) + 2);                                \
    __builtin_amdgcn_s_barrier();                                              \
    __builtin_amdgcn_s_setprio(1);                                             \
    MMA_PH(0, 1);                                                              \
    __builtin_amdgcn_s_setprio(0);                                             \
    __builtin_amdgcn_s_barrier();                                              \
    /* phase 3: A-high reads; stage B1(t+2) */                                 \
    DS_A(BUF, 1);                                                              \
    if ((MODE) == 0) STAGE_B(BUF, 1, (TT) + 2);                                \
    __builtin_amdgcn_s_barrier();                                              \
    asm volatile("s_waitcnt lgkmcnt(0)");                                      \
    __builtin_amdgcn_sched_barrier(0);                                         \
    __builtin_amdgcn_s_setprio(1);                                             \
    MMA_PH(1, 0);                                                              \
    __builtin_amdgcn_s_setprio(0);                                             \
    __builtin_amdgcn_s_barrier();                                              \
    /* phase 4: stage A0(t+2) (A-high last read in ph3); counted vmcnt */      \
    if ((MODE) == 0) STAGE_A(BUF, 0, (TT) + 2);                                \
    __builtin_amdgcn_s_barrier();                                              \
    __builtin_amdgcn_s_setprio(1);                                             \
    MMA_PH(1, 1);                                                              \
    __builtin_amdgcn_s_setprio(0);                                             \
    if ((MODE) == 0) {                                                         \
      asm volatile("s_waitcnt vmcnt(%0)" ::"i"(VM_N));                         \
    } else if ((MODE) == 1) {                                                  \
      asm volatile("s_waitcnt vmcnt(0)");                                      \
    }                                                                          \
    __builtin_amdgcn_s_barrier();                                              \
  }

  // prologue: tile0 fully + tile1's first 3 half-tiles; keep 3 in flight
  STAGE_B(0, 0, 0); STAGE_B(0, 1, 0); STAGE_A(0, 0, 0); STAGE_A(0, 1, 0);
  STAGE_B(1, 0, 1); STAGE_B(1, 1, 1); STAGE_A(1, 0, 1);
  asm volatile("s_waitcnt vmcnt(%0)" ::"i"(VM_N));
  __builtin_amdgcn_s_barrier();

  for (int t = 0; t < NTK - 2; ++t) KTILE(t & 1, t, 0);
  KTILE(0, NTK - 2, 1);   // NTK even -> parity 0
  KTILE(1, 0, 2);

#undef KTILE
#undef MMA_PH
#undef DS_B
#undef DS_A
#undef STAGE_B
#undef STAGE_A

  // epilogue: C/D frag layout col=l16, row=quad*4+r (m89/m91)
#pragma unroll
  for (int i = 0; i < 8; i++)
#pragma unroll
    for (int j = 0; j < NF; j++) {
      const int col = n0 + wn * WTN + j * 16 + l16;
#pragma unroll
      for (int r = 0; r < 4; r++) {
        const int row = m0 + wm * 128 + i * 16 + quad * 4 + r;
        const size_t idx2 = (size_t)row * N_ + col;
        float v = acc[i][j][r];
        if (EPI == 0) {
          ((bf16*)C)[idx2] = (bf16)v;
        } else if (EPI == 1) {
          ((float*)C)[idx2] = v + resid[idx2];
        } else if (EPI == 2) {
          v += bias[col];
          // tanh-form GELU: max |delta| vs exact ~1e-3 << bf16 noise
          const float u = 1.5957691216f * (v + 0.044715f * v * v * v);
          v = v / (1.0f + __expf(-u));
          ((bf16*)C)[idx2] = (bf16)v;
        } else {
          ((float*)C)[idx2] = v + bias[col] + resid[idx2];
        }
      }
    }
}

// ---------------------------------------------------------------------------
// Flash attention (causal), fixed-base softmax.  Q pre-scaled by 1/8.
// (unchanged this round)
// ---------------------------------------------------------------------------
__global__ __launch_bounds__(256, 6) void flash_attn(
    const bf16* __restrict__ qkv, const bf16* __restrict__ vt, bf16* __restrict__ out) {
  const int bid = blockIdx.x;
  const int xcd = bid & 7;
  const int idx = bid >> 3;            // 0..127
  const int pr = idx & 15;
  const int bh = xcd + ((idx >> 4) << 3);
  const int b = bh >> 4, h = bh & 15;
  const int tid = threadIdx.x;
  const int lane = tid & 63, wave = tid >> 6;
  const int quad = lane >> 4, l16 = lane & 15;

  __shared__ __align__(16) bf16 Ks[64 * 64];
  __shared__ __align__(16) bf16 Vts[64 * 64];   // [d][key]
  __shared__ __align__(16) bf16 Ps[4][16][72];

  const size_t rowbase = (size_t)b * SEQ;
  const int s8 = (lane >> 3) & 7;
  const int cs = ((lane & 7) ^ s8) * 8;          // swizzled fetch col (elems)
  const int xk = l16 & 7;                        // read-side XOR key
  const bf16* kbase = qkv + rowbase * QKVN + EMB + h * HD;
  const bf16* vbase = vt + (size_t)(bh * HD) * SEQ;

#pragma unroll 1
  for (int half = 0; half < 2; half++) {
    const int qt = half ? pr : 31 - pr;           // heavy tile first
    const int qrow_a = qt * 64 + wave * 16 + l16;
    const bf16* qptr = qkv + (rowbase + qrow_a) * QKVN + h * HD;
    const bf16x8 qf0 = *(const bf16x8*)(qptr + quad * 8);
    const bf16x8 qf1 = *(const bf16x8*)(qptr + 32 + quad * 8);
    f32x4 o0 = {}, o1 = {}, o2 = {}, o3 = {};
    f32x4 lsum = {};
    const int qrow_c = qt * 64 + wave * 16 + quad * 4;

    const bf16* kp = kbase + (size_t)(wave * 8 + s8) * QKVN + cs;
    const bf16* vp = vbase + (size_t)(wave * 8 + s8) * SEQ + cs;

#pragma unroll 1
    for (int kt = 0; kt <= qt; kt++) {
      __syncthreads();
      gl2lds16(kp + (size_t)kt * 64 * QKVN, &Ks[(wave * 8) * 64]);
      gl2lds16(kp + (size_t)(kt * 64 + 32) * QKVN, &Ks[(32 + wave * 8) * 64]);
      gl2lds16(vp + kt * 64, &Vts[(wave * 8) * 64]);
      gl2lds16(vp + (size_t)32 * SEQ + kt * 64, &Vts[(32 + wave * 8) * 64]);
      __syncthreads();

      if (kt < qt) {
#pragma unroll
        for (int j = 0; j < 4; j++) {
          const int rr = (j * 16 + l16) * 64;
          const bf16x8 kf0 = *(const bf16x8*)&Ks[rr + (quad ^ xk) * 8];
          const bf16x8 kf1 = *(const bf16x8*)&Ks[rr + ((4 + quad) ^ xk) * 8];
          f32x4 a = {};
          a = __builtin_amdgcn_mfma_f32_16x16x32_bf16(qf0, kf0, a, 0, 0, 0);
          a = __builtin_amdgcn_mfma_f32_16x16x32_bf16(qf1, kf1, a, 0, 0, 0);
#pragma unroll
          for (int r = 0; r < 4; r++) {
            const float pj = __expf(a[r]);
            lsum[r] += pj;
            Ps[wave][quad * 4 + r][j * 16 + l16] = (bf16)pj;
          }
        }
      } else {
#pragma unroll
        for (int j = 0; j < 4; j++) {
          if (j > wave) {
#pragma unroll
            for (int r = 0; r < 4; r++)
              Ps[wave][quad * 4 + r][j * 16 + l16] = (bf16)0.0f;
          } else {
            const int rr = (j * 16 + l16) * 64;
            const bf16x8 kf0 = *(const bf16x8*)&Ks[rr + (quad ^ xk) * 8];
            const bf16x8 kf1 = *(const bf16x8*)&Ks[rr + ((4 + quad) ^ xk) * 8];
            f32x4 a = {};
            a = __builtin_amdgcn_mfma_f32_16x16x32_bf16(qf0, kf0, a, 0, 0, 0);
            a = __builtin_amdgcn_mfma_f32_16x16x32_bf16(qf1, kf1, a, 0, 0, 0);
            if (j == wave) {
#pragma unroll
              for (int r = 0; r < 4; r++) {
                const float v = (l16 > quad * 4 + r) ? -INFINITY : a[r];
                const float pj = __expf(v);
                lsum[r] += pj;
                Ps[wave][quad * 4 + r][j * 16 + l16] = (bf16)pj;
              }
            } else {
#pragma unroll
              for (int r = 0; r < 4; r++) {
                const float pj = __expf(a[r]);
                lsum[r] += pj;
                Ps[wave][quad * 4 + r][j * 16 + l16] = (bf16)pj;
              }
            }
          }
        }
      }

      const bf16x8 af0 = *(const bf16x8*)&Ps[wave][l16][quad * 8];
      const bf16x8 af1 = *(const bf16x8*)&Ps[wave][l16][32 + quad * 8];
#pragma unroll
      for (int j = 0; j < 4; j++) {
        const int rr = (j * 16 + l16) * 64;
        const bf16x8 vf0 = *(const bf16x8*)&Vts[rr + (quad ^ xk) * 8];
        const bf16x8 vf1 = *(const bf16x8*)&Vts[rr + ((4 + quad) ^ xk) * 8];
        f32x4& oj = (j == 0) ? o0 : (j == 1) ? o1 : (j == 2) ? o2 : o3;
        oj = __builtin_amdgcn_mfma_f32_16x16x32_bf16(af0, vf0, oj, 0, 0, 0);
        oj = __builtin_amdgcn_mfma_f32_16x16x32_bf16(af1, vf1, oj, 0, 0, 0);
      }
    }

#pragma unroll
    for (int r = 0; r < 4; r++) {
      float ls = lsum[r];
      ls += __shfl_xor(ls, 1);
      ls += __shfl_xor(ls, 2);
      ls += __shfl_xor(ls, 4);
      ls += __shfl_xor(ls, 8);
      const float iv = 1.0f / ls;
      bf16* op = out + (rowbase + qrow_c + r) * EMB + h * HD;
      op[0 + l16] = (bf16)(o0[r] * iv);
      op[16 + l16] = (bf16)(o1[r] * iv);
      op[32 + l16] = (bf16)(o2[r] * iv);
      op[48 + l16] = (bf16)(o3[r] * iv);
    }
  }
}

// ---------------------------------------------------------------------------
extern "C" void kernel_launch(void* const* d_in, const int* in_sizes, int n_in,
                              void* d_out, int out_size, void* d_ws, size_t ws_size,
                              hipStream_t stream) {
  const float* x     = (const float*)d_in[0];
  const float* Wq    = (const float*)d_in[1];
  const float* Wk    = (const float*)d_in[2];
  const float* Wv    = (const float*)d_in[3];
  const float* Wo    = (const float*)d_in[4];
  const float* ln1_g = (const float*)d_in[5];
  const float* ln1_b = (const float*)d_in[6];
  const float* ln2_g = (const float*)d_in[7];
  const float* ln2_b = (const float*)d_in[8];
  const float* W1    = (const float*)d_in[9];
  const float* b1    = (const float*)d_in[10];
  const float* W2    = (const float*)d_in[11];
  const float* b2    = (const float*)d_in[12];
  float* out = (float*)d_out;  // doubles as x2 (post-attention residual state)

  bf16* p = (bf16*)d_ws;
  bf16* wqkv_t = p;                 p += (size_t)QKVN * EMB;   // [3072][1024]
  bf16* wo_t   = p;                 p += (size_t)EMB * EMB;    // [1024][1024]
  bf16* w1_t   = p;                 p += (size_t)FFN * EMB;    // [4096][1024]
  bf16* w2_t   = p;                 p += (size_t)EMB * FFN;    // [1024][4096]
  bf16* h      = p;                 p += (size_t)ROWS * EMB;   // LN out; aliased as vt
  bf16* qkv    = p;                 p += (size_t)ROWS * QKVN;  // [8192][3072]
  bf16* attn_o = p;                 p += (size_t)ROWS * EMB;   // [8192][1024]
  bf16* ffn1   = p;                 /* [8192][4096] */
  bf16* vt     = h;  // alias: h (LN1 out) is dead once QKV GEMM completes

  // 1) weight transpose-casts (Wq folds the 1/8 attention scale)
  transpose_cast<<<dim3(32, 32), 256, 0, stream>>>(Wq, wqkv_t, EMB, EMB, 0.125f);
  transpose_cast<<<dim3(32, 32), 256, 0, stream>>>(Wk, wqkv_t + (size_t)EMB * EMB, EMB, EMB, 1.0f);
  transpose_cast<<<dim3(32, 32), 256, 0, stream>>>(Wv, wqkv_t + (size_t)2 * EMB * EMB, EMB, EMB, 1.0f);
  transpose_cast<<<dim3(32, 32), 256, 0, stream>>>(Wo, wo_t, EMB, EMB, 1.0f);
  transpose_cast<<<dim3(128, 32), 256, 0, stream>>>(W1, w1_t, EMB, FFN, 1.0f);
  transpose_cast<<<dim3(32, 128), 256, 0, stream>>>(W2, w2_t, FFN, EMB, 1.0f);

  // 2) LN1
  layernorm_bf16<<<ROWS, 256, 0, stream>>>(x, ln1_g, ln1_b, h);

  // 3) fused QKV projection (256x256 tiles, 384 blocks)
  gemm8p<0, QKVN, EMB, 256><<<dim3((QKVN / 256) * (ROWS / 256)), 512, 0, stream>>>(
      h, wqkv_t, qkv, nullptr, nullptr);

  // 4) V transpose (h is dead now; vt aliases it)
  v_transpose<<<dim3(SEQ / 32, HD / 32, 64), 256, 0, stream>>>(qkv, vt);

  // 5) causal flash attention (1D grid, XCD-aware decode)
  flash_attn<<<1024, 256, 0, stream>>>(qkv, vt, attn_o);

  // 6) output projection + residual -> x2 (in d_out)  (256x128, 256 blocks)
  gemm8p<1, EMB, EMB, 128><<<dim3((EMB / 128) * (ROWS / 256)), 512, 0, stream>>>(
      attn_o, wo_t, out, nullptr, x);

  // 7) LN2 (overwrites vt alias — flash is done)
  layernorm_bf16<<<ROWS, 256, 0, stream>>>(out, ln2_g, ln2_b, h);

  // 8) FFN up + GELU (tanh form)  (256x256, 512 blocks)
  gemm8p<2, FFN, EMB, 256><<<dim3((FFN / 256) * (ROWS / 256)), 512, 0, stream>>>(
      h, w1_t, ffn1, b1, nullptr);

  // 9) FFN down + bias + residual -> final out  (256x128, 256 blocks)
  gemm8p<3, EMB, FFN, 128><<<dim3((EMB / 128) * (ROWS / 256)), 512, 0, stream>>>(
      ffn1, w2_t, out, b2, out);
}

// Round 2
// 507.474 us; speedup vs baseline: 1.0710x; 1.0710x over previous
//
#include <hip/hip_runtime.h>
#include <hip/hip_bf16.h>
#include <math.h>

typedef __bf16 bf16;
typedef bf16 bf16x8 __attribute__((ext_vector_type(8)));
typedef bf16 bf16x4 __attribute__((ext_vector_type(4)));
typedef float f32x4 __attribute__((ext_vector_type(4)));

#define ROWS 8192      // B*S = 4*2048
#define EMB  1024
#define NH_  16
#define HD   64
#define FFN  4096
#define QKVN 3072
#define SEQ  2048

// async global->LDS, 16B per lane; LDS dest is wave-uniform base + lane*16
__device__ __forceinline__ void gl2lds16(const bf16* g, bf16* l) {
  __builtin_amdgcn_global_load_lds((const __attribute__((address_space(1))) void*)g,
                                   (__attribute__((address_space(3))) void*)l, 16, 0, 0);
}

// ---------------------------------------------------------------------------
// Transpose-cast: W [K][N] fp32 -> Wt [N][K] bf16 (times scale).
// grid (N/32, K/32), 256 thr.
// ---------------------------------------------------------------------------
__global__ void transpose_cast(const float* __restrict__ W, bf16* __restrict__ Wt,
                               int K, int N, float scale) {
  __shared__ float tile[32][33];
  const int n0 = blockIdx.x * 32, k0 = blockIdx.y * 32;
  const int tx = threadIdx.x & 31, ty = threadIdx.x >> 5;  // ty 0..7
#pragma unroll
  for (int i = 0; i < 32; i += 8)
    tile[ty + i][tx] = W[(size_t)(k0 + ty + i) * N + n0 + tx];
  __syncthreads();
#pragma unroll
  for (int i = 0; i < 32; i += 8)
    Wt[(size_t)(n0 + ty + i) * K + k0 + tx] = (bf16)(tile[tx][ty + i] * scale);
}

// ---------------------------------------------------------------------------
// V transpose: qkv V-part [b*2048+s][2048 + h*64 + d] -> vt[(bh*64+d)*2048+s]
// ---------------------------------------------------------------------------
__global__ void v_transpose(const bf16* __restrict__ qkv, bf16* __restrict__ vt) {
  __shared__ bf16 tile[32][33];
  const int s0 = blockIdx.x * 32, d0 = blockIdx.y * 32, bh = blockIdx.z;
  const int b = bh >> 4, h = bh & 15;
  const int tx = threadIdx.x & 31, ty = threadIdx.x >> 5;
#pragma unroll
  for (int i = 0; i < 32; i += 8)
    tile[ty + i][tx] = qkv[(size_t)(b * SEQ + s0 + ty + i) * QKVN + 2 * EMB + h * HD + d0 + tx];
  __syncthreads();
#pragma unroll
  for (int i = 0; i < 32; i += 8)
    vt[(size_t)(bh * HD + d0 + ty + i) * SEQ + s0 + tx] = tile[tx][ty + i];
}

// ---------------------------------------------------------------------------
// LayerNorm fp32 -> bf16.  One block (256 thr) per row of 1024.
// ---------------------------------------------------------------------------
__global__ void layernorm_bf16(const float* __restrict__ x, const float* __restrict__ g,
                               const float* __restrict__ b, bf16* __restrict__ out) {
  const int row = blockIdx.x;
  const int t = threadIdx.x;
  const float4 v = ((const float4*)(x + (size_t)row * EMB))[t];
  float s = v.x + v.y + v.z + v.w;
  float ss = v.x * v.x + v.y * v.y + v.z * v.z + v.w * v.w;
#pragma unroll
  for (int off = 32; off; off >>= 1) {
    s += __shfl_down(s, off);
    ss += __shfl_down(ss, off);
  }
  __shared__ float sbuf[8];
  const int wave = t >> 6, lane = t & 63;
  if (lane == 0) { sbuf[wave] = s; sbuf[4 + wave] = ss; }
  __syncthreads();
  if (t == 0) {
    float S = sbuf[0] + sbuf[1] + sbuf[2] + sbuf[3];
    float SS = sbuf[4] + sbuf[5] + sbuf[6] + sbuf[7];
    float mu = S * (1.0f / EMB);
    float var = SS * (1.0f / EMB) - mu * mu;
    sbuf[0] = mu;
    sbuf[1] = rsqrtf(var + 1e-5f);
  }
  __syncthreads();
  const float mu = sbuf[0], rs = sbuf[1];
  const float4 gv = ((const float4*)g)[t];
  const float4 bv = ((const float4*)b)[t];
  bf16x4 o;
  o[0] = (bf16)((v.x - mu) * rs * gv.x + bv.x);
  o[1] = (bf16)((v.y - mu) * rs * gv.y + bv.y);
  o[2] = (bf16)((v.z - mu) * rs * gv.z + bv.z);
  o[3] = (bf16)((v.w - mu) * rs * gv.w + bv.w);
  *(bf16x4*)(out + (size_t)row * EMB + t * 4) = o;
}

// ---------------------------------------------------------------------------
// 8-phase 256-wide GEMM (HK-style schedule in plain HIP, per guide §5):
//   C[M=8192][N] = A[M][K](bf16 rm) * Bt[N][K]^T, BM=256, BK=64, 512 thr
//   (8 waves, 2M x 4N), BN in {256,128}.  LDS XOR-swizzle (chunk c of row r
//   at c^(r&7)); raw s_barrier + counted vmcnt (never 0 in the main loop).
//   Per K-tile: 4 phases, each {ds_read subtile | stage one half-tile |
//   barrier | lgkmcnt(0) | setprio(1) MFMA setprio(0) | barrier}.
//   Stage stream per tile t: [A1(t+1), B0(t+2), B1(t+2), A0(t+2)].
// XCD decode (round-0-proven locality): XCD = lin&7 owns m-tiles
//   [xcd*4, xcd*4+4), m cycles fastest within the XCD so the per-XCD A-slice
//   K-step (1024 rows x 64 = 128 KB) + B K-slice stay L2-resident; A is
//   fetched ~once from HBM instead of once per XCD.
// Epilogues: 0=bf16  1=+resid f32  2=+bias,GELU(tanh) bf16  3=+bias+resid f32
// ---------------------------------------------------------------------------
template <int EPI, int N_, int K_, int BN_>
__global__ __launch_bounds__(512, 2) void gemm8p(
    const bf16* __restrict__ A, const bf16* __restrict__ Bt, void* __restrict__ C,
    const float* __restrict__ bias, const float* __restrict__ resid) {
  constexpr int K = K_;
  constexpr int NF = BN_ / 64;        // B frags per wave (4 or 2)
  constexpr int NHF = NF / 2;         // frags per N-half (2 or 1)
  constexpr int WTN = BN_ / 4;        // per-wave N extent (64 or 32)
  constexpr int BRH = BN_ / 2;        // B staging-half rows (128 or 64)
  constexpr int BCALLS = BRH / 64;    // gl2lds calls per B half (2 or 1)
  constexpr int VM_N = 2 * BCALLS + 2;  // steady-state counted vmcnt
  constexpr int MT = ROWS / 256;
  constexpr int NT = N_ / BN_;
  constexpr int NTK = K / 64;
  constexpr int MLOC = MT / 8;        // m-tiles per XCD (4)
  static_assert(MT % 8 == 0, "M-tiles must split evenly over 8 XCDs");
  static_assert(NTK >= 4 && (NTK % 2) == 0, "K-tile count must be even >=4");

  __shared__ __align__(16) bf16 As[2][256 * 64];   // 64 KB
  __shared__ __align__(16) bf16 Bs[2][BN_ * 64];   // 64/32 KB

  const int tid = threadIdx.x;
  const int lane = tid & 63, wave = tid >> 6;
  const int wm = wave >> 2, wn = wave & 3;         // 2M x 4N wave grid
  const int quad = lane >> 4, l16 = lane & 15;
  const int srow = lane >> 3, ch = lane & 7;       // staging row/chunk in 8x8
  const int xr = l16 & 7;                          // read-side XOR key

  // XCD-aware decode: HW round-robins consecutive blockIdx across XCDs.
  const int lin = blockIdx.x;
  const int xcd = lin & 7;
  const int idx = lin >> 3;
  const int m0 = (xcd * MLOC + (idx % MLOC)) * 256;
  const int n0 = (idx / MLOC) * BN_;

  // staging base pointers: pre-swizzled global column so linear LDS dest
  // yields chunk c of row r at position c^(r&7)  (both-sides rule #21)
  const bf16* a_src = A + (size_t)(m0 + wave * 8 + srow) * K + (ch ^ srow) * 8;
  const bf16* b_src = Bt + (size_t)(n0 + wave * 8 + srow) * K + (ch ^ srow) * 8;

  f32x4 acc[8][NF] = {};
  bf16x8 af[4][2];      // current A half-subtile (reloaded in ph3)
  bf16x8 bfr[NF][2];    // all B frags for this K-tile (loaded in ph1)

#define STAGE_A(BUF, HH, TT)                                                   \
  {                                                                            \
    _Pragma("unroll") for (int q = 0; q < 2; q++)                              \
        gl2lds16(a_src + (size_t)((HH)*128 + q * 64) * K + (size_t)(TT)*64,    \
                 &As[(BUF)][((HH)*128 + q * 64 + wave * 8) * 64]);             \
  }
#define STAGE_B(BUF, HH, TT)                                                   \
  {                                                                            \
    _Pragma("unroll") for (int q = 0; q < BCALLS; q++)                         \
        gl2lds16(b_src + (size_t)((HH)*BRH + q * 64) * K + (size_t)(TT)*64,    \
                 &Bs[(BUF)][((HH)*BRH + q * 64 + wave * 8) * 64]);             \
  }
#define DS_A(BUF, HH)                                                          \
  {                                                                            \
    _Pragma("unroll") for (int i = 0; i < 4; i++)                              \
        _Pragma("unroll") for (int ks = 0; ks < 2; ks++)                       \
            af[i][ks] = *(const bf16x8*)&As[(BUF)][                            \
                (wm * 128 + (HH)*64 + i * 16 + l16) * 64 +                     \
                (((ks * 4 + quad) ^ xr) * 8)];                                 \
  }
#define DS_B(BUF)                                                              \
  {                                                                            \
    _Pragma("unroll") for (int j = 0; j < NF; j++)                             \
        _Pragma("unroll") for (int ks = 0; ks < 2; ks++)                       \
            bfr[j][ks] = *(const bf16x8*)&Bs[(BUF)][                           \
                (wn * WTN + j * 16 + l16) * 64 +                               \
                (((ks * 4 + quad) ^ xr) * 8)];                                 \
  }
#define MMA_PH(IH, JH)                                                         \
  {                                                                            \
    _Pragma("unroll") for (int i = 0; i < 4; i++)                              \
        _Pragma("unroll") for (int jj = 0; jj < NHF; jj++)                     \
            _Pragma("unroll") for (int ks = 0; ks < 2; ks++)                   \
                acc[(IH)*4 + i][(JH)*NHF + jj] =                               \
                    __builtin_amdgcn_mfma_f32_16x16x32_bf16(                   \
                        af[i][ks], bfr[(JH)*NHF + jj][ks],                     \
                        acc[(IH)*4 + i][(JH)*NHF + jj], 0, 0, 0);              \
  }
// MODE: 0 = steady (full stage + vmcnt(VM_N)), 1 = t==NTK-2 (only A1(t+1),
// vmcnt(0)), 2 = last tile (no stages, no vmcnt)
#define KTILE(BUF, TT, MODE)                                                   \
  {                                                                            \
    /* phase 1: A-low + all B reads; stage A1(t+1) into other buffer */        \
    DS_A(BUF, 0);                                                              \
    DS_B(BUF);                                                                 \
    if ((MODE) < 2) STAGE_A((BUF) ^ 1, 1, (TT) + 1);                           \
    __builtin_amdgcn_s_barrier();                                              \
    asm volatile("s_waitcnt lgkmcnt(0)");                                      \
    __builtin_amdgcn_sched_barrier(0);                                         \
    __builtin_amdgcn_s_setprio(1);                                             \
    MMA_PH(0, 0);                                                              \
    __builtin_amdgcn_s_setprio(0);                                             \
    __builtin_amdgcn_s_barrier();                                              \
    /* phase 2: stage B0(t+2) (B region last read in ph1) */                   \
    if ((MODE) == 0) STAGE_B(BUF, 0, (TT) + 2);                                \
    __builtin_amdgcn_s_barrier();                                              \
    __builtin_amdgcn_s_setprio(1);                                             \
    MMA_PH(0, 1);                                                              \
    __builtin_amdgcn_s_setprio(0);                                             \
    __builtin_amdgcn_s_barrier();                                              \
    /* phase 3: A-high reads; stage B1(t+2) */                                 \
    DS_A(BUF, 1);                                                              \
    if ((MODE) == 0) STAGE_B(BUF, 1, (TT) + 2);                                \
    __builtin_amdgcn_s_barrier();                                              \
    asm volatile("s_waitcnt lgkmcnt(0)");                                      \
    __builtin_amdgcn_sched_barrier(0);                                         \
    __builtin_amdgcn_s_setprio(1);                                             \
    MMA_PH(1, 0);                                                              \
    __builtin_amdgcn_s_setprio(0);                                             \
    __builtin_amdgcn_s_barrier();                                              \
    /* phase 4: stage A0(t+2) (A-high last read in ph3); counted vmcnt */      \
    if ((MODE) == 0) STAGE_A(BUF, 0, (TT) + 2);                                \
    __builtin_amdgcn_s_barrier();                                              \
    __builtin_amdgcn_s_setprio(1);                                             \
    MMA_PH(1, 1);                                                              \
    __builtin_amdgcn_s_setprio(0);                                             \
    if ((MODE) == 0) {                                                         \
      asm volatile("s_waitcnt vmcnt(%0)" ::"i"(VM_N));                         \
    } else if ((MODE) == 1) {                                                  \
      asm volatile("s_waitcnt vmcnt(0)");                                      \
    }                                                                          \
    __builtin_amdgcn_s_barrier();                                              \
  }

  // prologue: tile0 fully + tile1's first 3 half-tiles; keep 3 in flight
  STAGE_B(0, 0, 0); STAGE_B(0, 1, 0); STAGE_A(0, 0, 0); STAGE_A(0, 1, 0);
  STAGE_B(1, 0, 1); STAGE_B(1, 1, 1); STAGE_A(1, 0, 1);
  asm volatile("s_waitcnt vmcnt(%0)" ::"i"(VM_N));
  __builtin_amdgcn_s_barrier();

  for (int t = 0; t < NTK - 2; ++t) KTILE(t & 1, t, 0);
  KTILE(0, NTK - 2, 1);   // NTK even -> parity 0
  KTILE(1, 0, 2);

#undef KTILE
#undef MMA_PH
#undef DS_B
#undef DS_A
#undef STAGE_B
#undef STAGE_A

  // epilogue: C/D frag layout col=l16, row=quad*4+r (m89/m91)
#pragma unroll
  for (int i = 0; i < 8; i++)
#pragma unroll
    for (int j = 0; j < NF; j++) {
      const int col = n0 + wn * WTN + j * 16 + l16;
#pragma unroll
      for (int r = 0; r < 4; r++) {
        const int row = m0 + wm * 128 + i * 16 + quad * 4 + r;
        const size_t idx2 = (size_t)row * N_ + col;
        float v = acc[i][j][r];
        if (EPI == 0) {
          ((bf16*)C)[idx2] = (bf16)v;
        } else if (EPI == 1) {
          ((float*)C)[idx2] = v + resid[idx2];
        } else if (EPI == 2) {
          v += bias[col];
          // tanh-form GELU: max |delta| vs exact ~1e-3 << bf16 noise
          const float u = 1.5957691216f * (v + 0.044715f * v * v * v);
          v = v / (1.0f + __expf(-u));
          ((bf16*)C)[idx2] = (bf16)v;
        } else {
          ((float*)C)[idx2] = v + bias[col] + resid[idx2];
        }
      }
    }
}

// ---------------------------------------------------------------------------
// Flash attention (causal), fixed-base softmax.  Q pre-scaled by 1/8.
// (unchanged this round)
// ---------------------------------------------------------------------------
__global__ __launch_bounds__(256, 6) void flash_attn(
    const bf16* __restrict__ qkv, const bf16* __restrict__ vt, bf16* __restrict__ out) {
  const int bid = blockIdx.x;
  const int xcd = bid & 7;
  const int idx = bid >> 3;            // 0..127
  const int pr = idx & 15;
  const int bh = xcd + ((idx >> 4) << 3);
  const int b = bh >> 4, h = bh & 15;
  const int tid = threadIdx.x;
  const int lane = tid & 63, wave = tid >> 6;
  const int quad = lane >> 4, l16 = lane & 15;

  __shared__ __align__(16) bf16 Ks[64 * 64];
  __shared__ __align__(16) bf16 Vts[64 * 64];   // [d][key]
  __shared__ __align__(16) bf16 Ps[4][16][72];

  const size_t rowbase = (size_t)b * SEQ;
  const int s8 = (lane >> 3) & 7;
  const int cs = ((lane & 7) ^ s8) * 8;          // swizzled fetch col (elems)
  const int xk = l16 & 7;                        // read-side XOR key
  const bf16* kbase = qkv + rowbase * QKVN + EMB + h * HD;
  const bf16* vbase = vt + (size_t)(bh * HD) * SEQ;

#pragma unroll 1
  for (int half = 0; half < 2; half++) {
    const int qt = half ? pr : 31 - pr;           // heavy tile first
    const int qrow_a = qt * 64 + wave * 16 + l16;
    const bf16* qptr = qkv + (rowbase + qrow_a) * QKVN + h * HD;
    const bf16x8 qf0 = *(const bf16x8*)(qptr + quad * 8);
    const bf16x8 qf1 = *(const bf16x8*)(qptr + 32 + quad * 8);
    f32x4 o0 = {}, o1 = {}, o2 = {}, o3 = {};
    f32x4 lsum = {};
    const int qrow_c = qt * 64 + wave * 16 + quad * 4;

    const bf16* kp = kbase + (size_t)(wave * 8 + s8) * QKVN + cs;
    const bf16* vp = vbase + (size_t)(wave * 8 + s8) * SEQ + cs;

#pragma unroll 1
    for (int kt = 0; kt <= qt; kt++) {
      __syncthreads();
      gl2lds16(kp + (size_t)kt * 64 * QKVN, &Ks[(wave * 8) * 64]);
      gl2lds16(kp + (size_t)(kt * 64 + 32) * QKVN, &Ks[(32 + wave * 8) * 64]);
      gl2lds16(vp + kt * 64, &Vts[(wave * 8) * 64]);
      gl2lds16(vp + (size_t)32 * SEQ + kt * 64, &Vts[(32 + wave * 8) * 64]);
      __syncthreads();

      if (kt < qt) {
#pragma unroll
        for (int j = 0; j < 4; j++) {
          const int rr = (j * 16 + l16) * 64;
          const bf16x8 kf0 = *(const bf16x8*)&Ks[rr + (quad ^ xk) * 8];
          const bf16x8 kf1 = *(const bf16x8*)&Ks[rr + ((4 + quad) ^ xk) * 8];
          f32x4 a = {};
          a = __builtin_amdgcn_mfma_f32_16x16x32_bf16(qf0, kf0, a, 0, 0, 0);
          a = __builtin_amdgcn_mfma_f32_16x16x32_bf16(qf1, kf1, a, 0, 0, 0);
#pragma unroll
          for (int r = 0; r < 4; r++) {
            const float pj = __expf(a[r]);
            lsum[r] += pj;
            Ps[wave][quad * 4 + r][j * 16 + l16] = (bf16)pj;
          }
        }
      } else {
#pragma unroll
        for (int j = 0; j < 4; j++) {
          if (j > wave) {
#pragma unroll
            for (int r = 0; r < 4; r++)
              Ps[wave][quad * 4 + r][j * 16 + l16] = (bf16)0.0f;
          } else {
            const int rr = (j * 16 + l16) * 64;
            const bf16x8 kf0 = *(const bf16x8*)&Ks[rr + (quad ^ xk) * 8];
            const bf16x8 kf1 = *(const bf16x8*)&Ks[rr + ((4 + quad) ^ xk) * 8];
            f32x4 a = {};
            a = __builtin_amdgcn_mfma_f32_16x16x32_bf16(qf0, kf0, a, 0, 0, 0);
            a = __builtin_amdgcn_mfma_f32_16x16x32_bf16(qf1, kf1, a, 0, 0, 0);
            if (j == wave) {
#pragma unroll
              for (int r = 0; r < 4; r++) {
                const float v = (l16 > quad * 4 + r) ? -INFINITY : a[r];
                const float pj = __expf(v);
                lsum[r] += pj;
                Ps[wave][quad * 4 + r][j * 16 + l16] = (bf16)pj;
              }
            } else {
#pragma unroll
              for (int r = 0; r < 4; r++) {
                const float pj = __expf(a[r]);
                lsum[r] += pj;
                Ps[wave][quad * 4 + r][j * 16 + l16] = (bf16)pj;
              }
            }
          }
        }
      }

      const bf16x8 af0 = *(const bf16x8*)&Ps[wave][l16][quad * 8];
      const bf16x8 af1 = *(const bf16x8*)&Ps[wave][l16][32 + quad * 8];
#pragma unroll
      for (int j = 0; j < 4; j++) {
        const int rr = (j * 16 + l16) * 64;
        const bf16x8 vf0 = *(const bf16x8*)&Vts[rr + (quad ^ xk) * 8];
        const bf16x8 vf1 = *(const bf16x8*)&Vts[rr + ((4 + quad) ^ xk) * 8];
        f32x4& oj = (j == 0) ? o0 : (j == 1) ? o1 : (j == 2) ? o2 : o3;
        oj = __builtin_amdgcn_mfma_f32_16x16x32_bf16(af0, vf0, oj, 0, 0, 0);
        oj = __builtin_amdgcn_mfma_f32_16x16x32_bf16(af1, vf1, oj, 0, 0, 0);
      }
    }

#pragma unroll
    for (int r = 0; r < 4; r++) {
      float ls = lsum[r];
      ls += __shfl_xor(ls, 1);
      ls += __shfl_xor(ls, 2);
      ls += __shfl_xor(ls, 4);
      ls += __shfl_xor(ls, 8);
      const float iv = 1.0f / ls;
      bf16* op = out + (rowbase + qrow_c + r) * EMB + h * HD;
      op[0 + l16] = (bf16)(o0[r] * iv);
      op[16 + l16] = (bf16)(o1[r] * iv);
      op[32 + l16] = (bf16)(o2[r] * iv);
      op[48 + l16] = (bf16)(o3[r] * iv);
    }
  }
}

// ---------------------------------------------------------------------------
extern "C" void kernel_launch(void* const* d_in, const int* in_sizes, int n_in,
                              void* d_out, int out_size, void* d_ws, size_t ws_size,
                              hipStream_t stream) {
  const float* x     = (const float*)d_in[0];
  const float* Wq    = (const float*)d_in[1];
  const float* Wk    = (const float*)d_in[2];
  const float* Wv    = (const float*)d_in[3];
  const float* Wo    = (const float*)d_in[4];
  const float* ln1_g = (const float*)d_in[5];
  const float* ln1_b = (const float*)d_in[6];
  const float* ln2_g = (const float*)d_in[7];
  const float* ln2_b = (const float*)d_in[8];
  const float* W1    = (const float*)d_in[9];
  const float* b1    = (const float*)d_in[10];
  const float* W2    = (const float*)d_in[11];
  const float* b2    = (const float*)d_in[12];
  float* out = (float*)d_out;  // doubles as x2 (post-attention residual state)

  bf16* p = (bf16*)d_ws;
  bf16* wqkv_t = p;                 p += (size_t)QKVN * EMB;   // [3072][1024]
  bf16* wo_t   = p;                 p += (size_t)EMB * EMB;    // [1024][1024]
  bf16* w1_t   = p;                 p += (size_t)FFN * EMB;    // [4096][1024]
  bf16* w2_t   = p;                 p += (size_t)EMB * FFN;    // [1024][4096]
  bf16* h      = p;                 p += (size_t)ROWS * EMB;   // LN out; aliased as vt
  bf16* qkv    = p;                 p += (size_t)ROWS * QKVN;  // [8192][3072]
  bf16* attn_o = p;                 p += (size_t)ROWS * EMB;   // [8192][1024]
  bf16* ffn1   = p;                 /* [8192][4096] */
  bf16* vt     = h;  // alias: h (LN1 out) is dead once QKV GEMM completes

  // 1) weight transpose-casts (Wq folds the 1/8 attention scale)
  transpose_cast<<<dim3(32, 32), 256, 0, stream>>>(Wq, wqkv_t, EMB, EMB, 0.125f);
  transpose_cast<<<dim3(32, 32), 256, 0, stream>>>(Wk, wqkv_t + (size_t)EMB * EMB, EMB, EMB, 1.0f);
  transpose_cast<<<dim3(32, 32), 256, 0, stream>>>(Wv, wqkv_t + (size_t)2 * EMB * EMB, EMB, EMB, 1.0f);
  transpose_cast<<<dim3(32, 32), 256, 0, stream>>>(Wo, wo_t, EMB, EMB, 1.0f);
  transpose_cast<<<dim3(128, 32), 256, 0, stream>>>(W1, w1_t, EMB, FFN, 1.0f);
  transpose_cast<<<dim3(32, 128), 256, 0, stream>>>(W2, w2_t, FFN, EMB, 1.0f);

  // 2) LN1
  layernorm_bf16<<<ROWS, 256, 0, stream>>>(x, ln1_g, ln1_b, h);

  // 3) fused QKV projection (256x256 tiles, 384 blocks)
  gemm8p<0, QKVN, EMB, 256><<<dim3((QKVN / 256) * (ROWS / 256)), 512, 0, stream>>>(
      h, wqkv_t, qkv, nullptr, nullptr);

  // 4) V transpose (h is dead now; vt aliases it)
  v_transpose<<<dim3(SEQ / 32, HD / 32, 64), 256, 0, stream>>>(qkv, vt);

  // 5) causal flash attention (1D grid, XCD-aware decode)
  flash_attn<<<1024, 256, 0, stream>>>(qkv, vt, attn_o);

  // 6) output projection + residual -> x2 (in d_out)  (256x128, 256 blocks)
  gemm8p<1, EMB, EMB, 128><<<dim3((EMB / 128) * (ROWS / 256)), 512, 0, stream>>>(
      attn_o, wo_t, out, nullptr, x);

  // 7) LN2 (overwrites vt alias — flash is done)
  layernorm_bf16<<<ROWS, 256, 0, stream>>>(out, ln2_g, ln2_b, h);

  // 8) FFN up + GELU (tanh form)  (256x256, 512 blocks)
  gemm8p<2, FFN, EMB, 256><<<dim3((FFN / 256) * (ROWS / 256)), 512, 0, stream>>>(
      h, w1_t, ffn1, b1, nullptr);

  // 9) FFN down + bias + residual -> final out  (256x128, 256 blocks)
  gemm8p<3, EMB, FFN, 128><<<dim3((EMB / 128) * (ROWS / 256)), 512, 0, stream>>>(
      ffn1, w2_t, out, b2, out);
}

// Round 3
// 495.656 us; speedup vs baseline: 1.0966x; 1.0238x over previous
//
#include <hip/hip_runtime.h>
#include <hip/hip_bf16.h>
#include <math.h>

typedef __bf16 bf16;
typedef bf16 bf16x8 __attribute__((ext_vector_type(8)));
typedef bf16 bf16x4 __attribute__((ext_vector_type(4)));
typedef float f32x4 __attribute__((ext_vector_type(4)));

#define ROWS 8192      // B*S = 4*2048
#define EMB  1024
#define NH_  16
#define HD   64
#define FFN  4096
#define QKVN 3072
#define SEQ  2048

// async global->LDS, 16B per lane; LDS dest is wave-uniform base + lane*16
__device__ __forceinline__ void gl2lds16(const bf16* g, bf16* l) {
  __builtin_amdgcn_global_load_lds((const __attribute__((address_space(1))) void*)g,
                                   (__attribute__((address_space(3))) void*)l, 16, 0, 0);
}

// ---------------------------------------------------------------------------
// Transpose-cast: W [K][N] fp32 -> Wt [N][K] bf16 (times scale).
// grid (N/32, K/32), 256 thr.
// ---------------------------------------------------------------------------
__global__ void transpose_cast(const float* __restrict__ W, bf16* __restrict__ Wt,
                               int K, int N, float scale) {
  __shared__ float tile[32][33];
  const int n0 = blockIdx.x * 32, k0 = blockIdx.y * 32;
  const int tx = threadIdx.x & 31, ty = threadIdx.x >> 5;  // ty 0..7
#pragma unroll
  for (int i = 0; i < 32; i += 8)
    tile[ty + i][tx] = W[(size_t)(k0 + ty + i) * N + n0 + tx];
  __syncthreads();
#pragma unroll
  for (int i = 0; i < 32; i += 8)
    Wt[(size_t)(n0 + ty + i) * K + k0 + tx] = (bf16)(tile[tx][ty + i] * scale);
}

// ---------------------------------------------------------------------------
// V transpose: qkv V-part [b*2048+s][2048 + h*64 + d] -> vt[(bh*64+d)*2048+s]
// ---------------------------------------------------------------------------
__global__ void v_transpose(const bf16* __restrict__ qkv, bf16* __restrict__ vt) {
  __shared__ bf16 tile[32][33];
  const int s0 = blockIdx.x * 32, d0 = blockIdx.y * 32, bh = blockIdx.z;
  const int b = bh >> 4, h = bh & 15;
  const int tx = threadIdx.x & 31, ty = threadIdx.x >> 5;
#pragma unroll
  for (int i = 0; i < 32; i += 8)
    tile[ty + i][tx] = qkv[(size_t)(b * SEQ + s0 + ty + i) * QKVN + 2 * EMB + h * HD + d0 + tx];
  __syncthreads();
#pragma unroll
  for (int i = 0; i < 32; i += 8)
    vt[(size_t)(bh * HD + d0 + ty + i) * SEQ + s0 + tx] = tile[tx][ty + i];
}

// ---------------------------------------------------------------------------
// LayerNorm fp32 -> bf16.  One block (256 thr) per row of 1024.
// ---------------------------------------------------------------------------
__global__ void layernorm_bf16(const float* __restrict__ x, const float* __restrict__ g,
                               const float* __restrict__ b, bf16* __restrict__ out) {
  const int row = blockIdx.x;
  const int t = threadIdx.x;
  const float4 v = ((const float4*)(x + (size_t)row * EMB))[t];
  float s = v.x + v.y + v.z + v.w;
  float ss = v.x * v.x + v.y * v.y + v.z * v.z + v.w * v.w;
#pragma unroll
  for (int off = 32; off; off >>= 1) {
    s += __shfl_down(s, off);
    ss += __shfl_down(ss, off);
  }
  __shared__ float sbuf[8];
  const int wave = t >> 6, lane = t & 63;
  if (lane == 0) { sbuf[wave] = s; sbuf[4 + wave] = ss; }
  __syncthreads();
  if (t == 0) {
    float S = sbuf[0] + sbuf[1] + sbuf[2] + sbuf[3];
    float SS = sbuf[4] + sbuf[5] + sbuf[6] + sbuf[7];
    float mu = S * (1.0f / EMB);
    float var = SS * (1.0f / EMB) - mu * mu;
    sbuf[0] = mu;
    sbuf[1] = rsqrtf(var + 1e-5f);
  }
  __syncthreads();
  const float mu = sbuf[0], rs = sbuf[1];
  const float4 gv = ((const float4*)g)[t];
  const float4 bv = ((const float4*)b)[t];
  bf16x4 o;
  o[0] = (bf16)((v.x - mu) * rs * gv.x + bv.x);
  o[1] = (bf16)((v.y - mu) * rs * gv.y + bv.y);
  o[2] = (bf16)((v.z - mu) * rs * gv.z + bv.z);
  o[3] = (bf16)((v.w - mu) * rs * gv.w + bv.w);
  *(bf16x4*)(out + (size_t)row * EMB + t * 4) = o;
}

// ---------------------------------------------------------------------------
// 8-phase 256-wide GEMM, v3 (template-faithful port):
//   C[M=8192][N] = A[M][K](bf16 rm) * Bt[N][K]^T, BM=256, BK=64, 512 thr
//   (8 waves, 2M x 4N), BN in {256,128}.  K-loop: 2 K-tiles/iter with
//   LITERAL buffer parity (static LDS addressing -> ds_read offset imms).
//   Per K-tile 4 phases, reads distributed 12/4/8/0:
//     ph1: ds A-half0 + B-half0, stage A1(t+1)->buf^1 | bar | lgkm0 | MMA(0,0)
//     ph2: ds B-half1,           stage B0(t+2)->buf   | bar | lgkm0 | MMA(0,1)
//     ph3: ds A-half1,           stage B1(t+2)->buf   | bar | lgkm0 | MMA(1,0)
//     ph4: (B-half0 kept in regs from ph1), stage A0(t+2) | bar | MMA(1,1)
//   Every stage targets a region whose last LDS read completed >=1 barrier
//   earlier (A0/B0 read ph1, B1 ph2, A1 ph3; B0 reused from REGS in ph3).
//   Counted vmcnt only at ph4 (VM_N = {B0,B1,A0}(t+2) in flight), never 0
//   in the main loop.  Peak live frag regs 64 (af 32 + bfr0 16 + bfr1 16).
// XCD decode: XCD = lin&7 owns m-tiles [xcd*4, xcd*4+4), m cycles fastest ->
//   per-XCD per-K-step working set (128 KB A-slice + <=256 KB B-slice) is
//   L2-resident; A fetched ~once from HBM.
// Epilogues: 0=bf16  1=+resid f32  2=+bias,GELU(tanh) bf16  3=+bias+resid f32
// ---------------------------------------------------------------------------
template <int EPI, int N_, int K_, int BN_>
__global__ __launch_bounds__(512, 2) void gemm8p(
    const bf16* __restrict__ A, const bf16* __restrict__ Bt, void* __restrict__ C,
    const float* __restrict__ bias, const float* __restrict__ resid) {
  constexpr int K = K_;
  constexpr int NF = BN_ / 64;        // B frags per wave (4 or 2)
  constexpr int NHF = NF / 2;         // frags per N-half (2 or 1)
  constexpr int WTN = BN_ / 4;        // per-wave N extent (64 or 32)
  constexpr int BRH = BN_ / 2;        // B staging-half rows (128 or 64)
  constexpr int BCALLS = BRH / 64;    // gl2lds calls per B half (2 or 1)
  constexpr int VM_N = 2 * BCALLS + 2;  // steady-state counted vmcnt
  constexpr int MT = ROWS / 256;
  constexpr int NT = N_ / BN_;
  constexpr int NTK = K / 64;
  constexpr int MLOC = MT / 8;        // m-tiles per XCD (4)
  static_assert(MT % 8 == 0, "M-tiles must split evenly over 8 XCDs");
  static_assert(NTK >= 4 && (NTK % 2) == 0, "K-tile count must be even >=4");

  __shared__ __align__(16) bf16 As[2][256 * 64];   // 64 KB
  __shared__ __align__(16) bf16 Bs[2][BN_ * 64];   // 64/32 KB

  const int tid = threadIdx.x;
  const int lane = tid & 63, wave = tid >> 6;
  const int wm = wave >> 2, wn = wave & 3;         // 2M x 4N wave grid
  const int quad = lane >> 4, l16 = lane & 15;
  const int srow = lane >> 3, ch = lane & 7;       // staging row/chunk in 8x8
  const int xr = l16 & 7;                          // read-side XOR key

  // XCD-aware decode: HW round-robins consecutive blockIdx across XCDs.
  const int lin = blockIdx.x;
  const int xcd = lin & 7;
  const int idx = lin >> 3;
  const int m0 = (xcd * MLOC + (idx % MLOC)) * 256;
  const int n0 = (idx / MLOC) * BN_;

  // staging base pointers: pre-swizzled global column so linear LDS dest
  // yields chunk c of row r at position c^(r&7)  (both-sides rule #21)
  const bf16* a_src = A + (size_t)(m0 + wave * 8 + srow) * K + (ch ^ srow) * 8;
  const bf16* b_src = Bt + (size_t)(n0 + wave * 8 + srow) * K + (ch ^ srow) * 8;

  f32x4 acc[8][NF] = {};
  bf16x8 af[4][2];       // current A half-subtile (ph1: half0, ph3: half1)
  bf16x8 b0r[NHF][2];    // B half0 frags (live ph1 -> ph4, no re-read)
  bf16x8 b1r[NHF][2];    // B half1 frags (live ph2 -> ph4)

#define STAGE_A(BUF, HH, TT)                                                   \
  {                                                                            \
    _Pragma("unroll") for (int q = 0; q < 2; q++)                              \
        gl2lds16(a_src + (size_t)((HH)*128 + q * 64) * K + (size_t)(TT)*64,    \
                 &As[(BUF)][((HH)*128 + q * 64 + wave * 8) * 64]);             \
  }
#define STAGE_B(BUF, HH, TT)                                                   \
  {                                                                            \
    _Pragma("unroll") for (int q = 0; q < BCALLS; q++)                         \
        gl2lds16(b_src + (size_t)((HH)*BRH + q * 64) * K + (size_t)(TT)*64,    \
                 &Bs[(BUF)][((HH)*BRH + q * 64 + wave * 8) * 64]);             \
  }
#define DS_A(BUF, HH)                                                          \
  {                                                                            \
    _Pragma("unroll") for (int i = 0; i < 4; i++)                              \
        _Pragma("unroll") for (int ks = 0; ks < 2; ks++)                       \
            af[i][ks] = *(const bf16x8*)&As[(BUF)][                            \
                (wm * 128 + (HH)*64 + i * 16 + l16) * 64 +                     \
                (((ks * 4 + quad) ^ xr) * 8)];                                 \
  }
#define DS_BH(BUF, JH, DST)                                                    \
  {                                                                            \
    _Pragma("unroll") for (int jj = 0; jj < NHF; jj++)                         \
        _Pragma("unroll") for (int ks = 0; ks < 2; ks++)                       \
            DST[jj][ks] = *(const bf16x8*)&Bs[(BUF)][                          \
                (wn * WTN + ((JH)*NHF + jj) * 16 + l16) * 64 +                 \
                (((ks * 4 + quad) ^ xr) * 8)];                                 \
  }
#define MMA_PH(IH, JH, BSRC)                                                   \
  {                                                                            \
    _Pragma("unroll") for (int i = 0; i < 4; i++)                              \
        _Pragma("unroll") for (int jj = 0; jj < NHF; jj++)                     \
            _Pragma("unroll") for (int ks = 0; ks < 2; ks++)                   \
                acc[(IH)*4 + i][(JH)*NHF + jj] =                               \
                    __builtin_amdgcn_mfma_f32_16x16x32_bf16(                   \
                        af[i][ks], BSRC[jj][ks],                               \
                        acc[(IH)*4 + i][(JH)*NHF + jj], 0, 0, 0);              \
  }
#define LGKM0()                                                                \
  asm volatile("s_waitcnt lgkmcnt(0)");                                        \
  __builtin_amdgcn_sched_barrier(0);
// MODE: 0 = steady (full stage + vmcnt(VM_N)), 1 = t==NTK-2 (only A1(t+1),
// vmcnt(0)), 2 = last tile (no stages, no vmcnt)
#define KTILE(BUF, TT, MODE)                                                   \
  {                                                                            \
    /* ph1: A-half0 + B-half0 reads; stage A1(t+1) into other buffer */        \
    DS_A(BUF, 0);                                                              \
    DS_BH(BUF, 0, b0r);                                                        \
    if ((MODE) < 2) STAGE_A((BUF) ^ 1, 1, (TT) + 1);                           \
    __builtin_amdgcn_s_barrier();                                              \
    LGKM0();                                                                   \
    __builtin_amdgcn_s_setprio(1);                                             \
    MMA_PH(0, 0, b0r);                                                         \
    __builtin_amdgcn_s_setprio(0);                                             \
    __builtin_amdgcn_s_barrier();                                              \
    /* ph2: B-half1 reads; stage B0(t+2) (B0 region last read ph1) */          \
    DS_BH(BUF, 1, b1r);                                                        \
    if ((MODE) == 0) STAGE_B(BUF, 0, (TT) + 2);                                \
    __builtin_amdgcn_s_barrier();                                              \
    LGKM0();                                                                   \
    __builtin_amdgcn_s_setprio(1);                                             \
    MMA_PH(0, 1, b1r);                                                         \
    __builtin_amdgcn_s_setprio(0);                                             \
    __builtin_amdgcn_s_barrier();                                              \
    /* ph3: A-half1 reads (B-half0 reused from regs); stage B1(t+2) */         \
    DS_A(BUF, 1);                                                              \
    if ((MODE) == 0) STAGE_B(BUF, 1, (TT) + 2);                                \
    __builtin_amdgcn_s_barrier();                                              \
    LGKM0();                                                                   \
    __builtin_amdgcn_s_setprio(1);                                             \
    MMA_PH(1, 0, b0r);                                                         \
    __builtin_amdgcn_s_setprio(0);                                             \
    __builtin_amdgcn_s_barrier();                                              \
    /* ph4: no reads; stage A0(t+2) (A0 region last read ph1); counted wait */ \
    if ((MODE) == 0) STAGE_A(BUF, 0, (TT) + 2);                                \
    __builtin_amdgcn_s_barrier();                                              \
    __builtin_amdgcn_s_setprio(1);                                             \
    MMA_PH(1, 1, b1r);                                                         \
    __builtin_amdgcn_s_setprio(0);                                             \
    if ((MODE) == 0) {                                                         \
      asm volatile("s_waitcnt vmcnt(%0)" ::"i"(VM_N));                         \
    } else if ((MODE) == 1) {                                                  \
      asm volatile("s_waitcnt vmcnt(0)");                                      \
    }                                                                          \
    __builtin_amdgcn_s_barrier();                                              \
  }

  // prologue: tile0 fully + tile1's first 3 half-tiles; keep 3 in flight
  STAGE_B(0, 0, 0); STAGE_B(0, 1, 0); STAGE_A(0, 0, 0); STAGE_A(0, 1, 0);
  STAGE_B(1, 0, 1); STAGE_B(1, 1, 1); STAGE_A(1, 0, 1);
  asm volatile("s_waitcnt vmcnt(%0)" ::"i"(VM_N));
  __builtin_amdgcn_s_barrier();

  // 2 K-tiles per iteration -> literal buffer parity (static LDS addressing)
  for (int t = 0; t < NTK - 2; t += 2) {
    KTILE(0, t, 0);
    KTILE(1, t + 1, 0);
  }
  KTILE(0, NTK - 2, 1);   // NTK even -> parity 0
  KTILE(1, 0, 2);

#undef KTILE
#undef LGKM0
#undef MMA_PH
#undef DS_BH
#undef DS_A
#undef STAGE_B
#undef STAGE_A

  // epilogue: C/D frag layout col=l16, row=quad*4+r (m89/m91)
#pragma unroll
  for (int i = 0; i < 8; i++)
#pragma unroll
    for (int j = 0; j < NF; j++) {
      const int col = n0 + wn * WTN + j * 16 + l16;
#pragma unroll
      for (int r = 0; r < 4; r++) {
        const int row = m0 + wm * 128 + i * 16 + quad * 4 + r;
        const size_t idx2 = (size_t)row * N_ + col;
        float v = acc[i][j][r];
        if (EPI == 0) {
          ((bf16*)C)[idx2] = (bf16)v;
        } else if (EPI == 1) {
          ((float*)C)[idx2] = v + resid[idx2];
        } else if (EPI == 2) {
          v += bias[col];
          // tanh-form GELU: max |delta| vs exact ~1e-3 << bf16 noise
          const float u = 1.5957691216f * (v + 0.044715f * v * v * v);
          v = v / (1.0f + __expf(-u));
          ((bf16*)C)[idx2] = (bf16)v;
        } else {
          ((float*)C)[idx2] = v + bias[col] + resid[idx2];
        }
      }
    }
}

// ---------------------------------------------------------------------------
// Flash attention (causal), fixed-base softmax.  Q pre-scaled by 1/8.
// (unchanged this round)
// ---------------------------------------------------------------------------
__global__ __launch_bounds__(256, 6) void flash_attn(
    const bf16* __restrict__ qkv, const bf16* __restrict__ vt, bf16* __restrict__ out) {
  const int bid = blockIdx.x;
  const int xcd = bid & 7;
  const int idx = bid >> 3;            // 0..127
  const int pr = idx & 15;
  const int bh = xcd + ((idx >> 4) << 3);
  const int b = bh >> 4, h = bh & 15;
  const int tid = threadIdx.x;
  const int lane = tid & 63, wave = tid >> 6;
  const int quad = lane >> 4, l16 = lane & 15;

  __shared__ __align__(16) bf16 Ks[64 * 64];
  __shared__ __align__(16) bf16 Vts[64 * 64];   // [d][key]
  __shared__ __align__(16) bf16 Ps[4][16][72];

  const size_t rowbase = (size_t)b * SEQ;
  const int s8 = (lane >> 3) & 7;
  const int cs = ((lane & 7) ^ s8) * 8;          // swizzled fetch col (elems)
  const int xk = l16 & 7;                        // read-side XOR key
  const bf16* kbase = qkv + rowbase * QKVN + EMB + h * HD;
  const bf16* vbase = vt + (size_t)(bh * HD) * SEQ;

#pragma unroll 1
  for (int half = 0; half < 2; half++) {
    const int qt = half ? pr : 31 - pr;           // heavy tile first
    const int qrow_a = qt * 64 + wave * 16 + l16;
    const bf16* qptr = qkv + (rowbase + qrow_a) * QKVN + h * HD;
    const bf16x8 qf0 = *(const bf16x8*)(qptr + quad * 8);
    const bf16x8 qf1 = *(const bf16x8*)(qptr + 32 + quad * 8);
    f32x4 o0 = {}, o1 = {}, o2 = {}, o3 = {};
    f32x4 lsum = {};
    const int qrow_c = qt * 64 + wave * 16 + quad * 4;

    const bf16* kp = kbase + (size_t)(wave * 8 + s8) * QKVN + cs;
    const bf16* vp = vbase + (size_t)(wave * 8 + s8) * SEQ + cs;

#pragma unroll 1
    for (int kt = 0; kt <= qt; kt++) {
      __syncthreads();
      gl2lds16(kp + (size_t)kt * 64 * QKVN, &Ks[(wave * 8) * 64]);
      gl2lds16(kp + (size_t)(kt * 64 + 32) * QKVN, &Ks[(32 + wave * 8) * 64]);
      gl2lds16(vp + kt * 64, &Vts[(wave * 8) * 64]);
      gl2lds16(vp + (size_t)32 * SEQ + kt * 64, &Vts[(32 + wave * 8) * 64]);
      __syncthreads();

      if (kt < qt) {
#pragma unroll
        for (int j = 0; j < 4; j++) {
          const int rr = (j * 16 + l16) * 64;
          const bf16x8 kf0 = *(const bf16x8*)&Ks[rr + (quad ^ xk) * 8];
          const bf16x8 kf1 = *(const bf16x8*)&Ks[rr + ((4 + quad) ^ xk) * 8];
          f32x4 a = {};
          a = __builtin_amdgcn_mfma_f32_16x16x32_bf16(qf0, kf0, a, 0, 0, 0);
          a = __builtin_amdgcn_mfma_f32_16x16x32_bf16(qf1, kf1, a, 0, 0, 0);
#pragma unroll
          for (int r = 0; r < 4; r++) {
            const float pj = __expf(a[r]);
            lsum[r] += pj;
            Ps[wave][quad * 4 + r][j * 16 + l16] = (bf16)pj;
          }
        }
      } else {
#pragma unroll
        for (int j = 0; j < 4; j++) {
          if (j > wave) {
#pragma unroll
            for (int r = 0; r < 4; r++)
              Ps[wave][quad * 4 + r][j * 16 + l16] = (bf16)0.0f;
          } else {
            const int rr = (j * 16 + l16) * 64;
            const bf16x8 kf0 = *(const bf16x8*)&Ks[rr + (quad ^ xk) * 8];
            const bf16x8 kf1 = *(const bf16x8*)&Ks[rr + ((4 + quad) ^ xk) * 8];
            f32x4 a = {};
            a = __builtin_amdgcn_mfma_f32_16x16x32_bf16(qf0, kf0, a, 0, 0, 0);
            a = __builtin_amdgcn_mfma_f32_16x16x32_bf16(qf1, kf1, a, 0, 0, 0);
            if (j == wave) {
#pragma unroll
              for (int r = 0; r < 4; r++) {
                const float v = (l16 > quad * 4 + r) ? -INFINITY : a[r];
                const float pj = __expf(v);
                lsum[r] += pj;
                Ps[wave][quad * 4 + r][j * 16 + l16] = (bf16)pj;
              }
            } else {
#pragma unroll
              for (int r = 0; r < 4; r++) {
                const float pj = __expf(a[r]);
                lsum[r] += pj;
                Ps[wave][quad * 4 + r][j * 16 + l16] = (bf16)pj;
              }
            }
          }
        }
      }

      const bf16x8 af0 = *(const bf16x8*)&Ps[wave][l16][quad * 8];
      const bf16x8 af1 = *(const bf16x8*)&Ps[wave][l16][32 + quad * 8];
#pragma unroll
      for (int j = 0; j < 4; j++) {
        const int rr = (j * 16 + l16) * 64;
        const bf16x8 vf0 = *(const bf16x8*)&Vts[rr + (quad ^ xk) * 8];
        const bf16x8 vf1 = *(const bf16x8*)&Vts[rr + ((4 + quad) ^ xk) * 8];
        f32x4& oj = (j == 0) ? o0 : (j == 1) ? o1 : (j == 2) ? o2 : o3;
        oj = __builtin_amdgcn_mfma_f32_16x16x32_bf16(af0, vf0, oj, 0, 0, 0);
        oj = __builtin_amdgcn_mfma_f32_16x16x32_bf16(af1, vf1, oj, 0, 0, 0);
      }
    }

#pragma unroll
    for (int r = 0; r < 4; r++) {
      float ls = lsum[r];
      ls += __shfl_xor(ls, 1);
      ls += __shfl_xor(ls, 2);
      ls += __shfl_xor(ls, 4);
      ls += __shfl_xor(ls, 8);
      const float iv = 1.0f / ls;
      bf16* op = out + (rowbase + qrow_c + r) * EMB + h * HD;
      op[0 + l16] = (bf16)(o0[r] * iv);
      op[16 + l16] = (bf16)(o1[r] * iv);
      op[32 + l16] = (bf16)(o2[r] * iv);
      op[48 + l16] = (bf16)(o3[r] * iv);
    }
  }
}

// ---------------------------------------------------------------------------
extern "C" void kernel_launch(void* const* d_in, const int* in_sizes, int n_in,
                              void* d_out, int out_size, void* d_ws, size_t ws_size,
                              hipStream_t stream) {
  const float* x     = (const float*)d_in[0];
  const float* Wq    = (const float*)d_in[1];
  const float* Wk    = (const float*)d_in[2];
  const float* Wv    = (const float*)d_in[3];
  const float* Wo    = (const float*)d_in[4];
  const float* ln1_g = (const float*)d_in[5];
  const float* ln1_b = (const float*)d_in[6];
  const float* ln2_g = (const float*)d_in[7];
  const float* ln2_b = (const float*)d_in[8];
  const float* W1    = (const float*)d_in[9];
  const float* b1    = (const float*)d_in[10];
  const float* W2    = (const float*)d_in[11];
  const float* b2    = (const float*)d_in[12];
  float* out = (float*)d_out;  // doubles as x2 (post-attention residual state)

  bf16* p = (bf16*)d_ws;
  bf16* wqkv_t = p;                 p += (size_t)QKVN * EMB;   // [3072][1024]
  bf16* wo_t   = p;                 p += (size_t)EMB * EMB;    // [1024][1024]
  bf16* w1_t   = p;                 p += (size_t)FFN * EMB;    // [4096][1024]
  bf16* w2_t   = p;                 p += (size_t)EMB * FFN;    // [1024][4096]
  bf16* h      = p;                 p += (size_t)ROWS * EMB;   // LN out; aliased as vt
  bf16* qkv    = p;                 p += (size_t)ROWS * QKVN;  // [8192][3072]
  bf16* attn_o = p;                 p += (size_t)ROWS * EMB;   // [8192][1024]
  bf16* ffn1   = p;                 /* [8192][4096] */
  bf16* vt     = h;  // alias: h (LN1 out) is dead once QKV GEMM completes

  // 1) weight transpose-casts (Wq folds the 1/8 attention scale)
  transpose_cast<<<dim3(32, 32), 256, 0, stream>>>(Wq, wqkv_t, EMB, EMB, 0.125f);
  transpose_cast<<<dim3(32, 32), 256, 0, stream>>>(Wk, wqkv_t + (size_t)EMB * EMB, EMB, EMB, 1.0f);
  transpose_cast<<<dim3(32, 32), 256, 0, stream>>>(Wv, wqkv_t + (size_t)2 * EMB * EMB, EMB, EMB, 1.0f);
  transpose_cast<<<dim3(32, 32), 256, 0, stream>>>(Wo, wo_t, EMB, EMB, 1.0f);
  transpose_cast<<<dim3(128, 32), 256, 0, stream>>>(W1, w1_t, EMB, FFN, 1.0f);
  transpose_cast<<<dim3(32, 128), 256, 0, stream>>>(W2, w2_t, FFN, EMB, 1.0f);

  // 2) LN1
  layernorm_bf16<<<ROWS, 256, 0, stream>>>(x, ln1_g, ln1_b, h);

  // 3) fused QKV projection (256x256 tiles, 384 blocks)
  gemm8p<0, QKVN, EMB, 256><<<dim3((QKVN / 256) * (ROWS / 256)), 512, 0, stream>>>(
      h, wqkv_t, qkv, nullptr, nullptr);

  // 4) V transpose (h is dead now; vt aliases it)
  v_transpose<<<dim3(SEQ / 32, HD / 32, 64), 256, 0, stream>>>(qkv, vt);

  // 5) causal flash attention (1D grid, XCD-aware decode)
  flash_attn<<<1024, 256, 0, stream>>>(qkv, vt, attn_o);

  // 6) output projection + residual -> x2 (in d_out)  (256x128, 256 blocks)
  gemm8p<1, EMB, EMB, 128><<<dim3((EMB / 128) * (ROWS / 256)), 512, 0, stream>>>(
      attn_o, wo_t, out, nullptr, x);

  // 7) LN2 (overwrites vt alias — flash is done)
  layernorm_bf16<<<ROWS, 256, 0, stream>>>(out, ln2_g, ln2_b, h);

  // 8) FFN up + GELU (tanh form)  (256x256, 512 blocks)
  gemm8p<2, FFN, EMB, 256><<<dim3((FFN / 256) * (ROWS / 256)), 512, 0, stream>>>(
      h, w1_t, ffn1, b1, nullptr);

  // 9) FFN down + bias + residual -> final out  (256x128, 256 blocks)
  gemm8p<3, EMB, FFN, 128><<<dim3((EMB / 128) * (ROWS / 256)), 512, 0, stream>>>(
      ffn1, w2_t, out, b2, out);
}

// Round 4
// 454.921 us; speedup vs baseline: 1.1948x; 1.0895x over previous
//
#include <hip/hip_runtime.h>
#include <hip/hip_bf16.h>
#include <math.h>

typedef __bf16 bf16;
typedef bf16 bf16x8 __attribute__((ext_vector_type(8)));
typedef bf16 bf16x4 __attribute__((ext_vector_type(4)));
typedef float f32x4 __attribute__((ext_vector_type(4)));

#define ROWS 8192      // B*S = 4*2048
#define EMB  1024
#define NH   16
#define HD   64
#define FFN  4096
#define QKVN 3072
#define SEQ  2048

// async global->LDS, 16B per lane; LDS dest is wave-uniform base + lane*16
__device__ __forceinline__ void gl2lds16(const bf16* g, bf16* l) {
  __builtin_amdgcn_global_load_lds((const __attribute__((address_space(1))) void*)g,
                                   (__attribute__((address_space(3))) void*)l, 16, 0, 0);
}

// ---------------------------------------------------------------------------
// Transpose-cast: W [K][N] fp32 -> Wt [N][K] bf16 (times scale).
// grid (N/32, K/32), 256 thr.
// ---------------------------------------------------------------------------
__global__ void transpose_cast(const float* __restrict__ W, bf16* __restrict__ Wt,
                               int K, int N, float scale) {
  __shared__ float tile[32][33];
  const int n0 = blockIdx.x * 32, k0 = blockIdx.y * 32;
  const int tx = threadIdx.x & 31, ty = threadIdx.x >> 5;  // ty 0..7
#pragma unroll
  for (int i = 0; i < 32; i += 8)
    tile[ty + i][tx] = W[(size_t)(k0 + ty + i) * N + n0 + tx];
  __syncthreads();
#pragma unroll
  for (int i = 0; i < 32; i += 8)
    Wt[(size_t)(n0 + ty + i) * K + k0 + tx] = (bf16)(tile[tx][ty + i] * scale);
}

// ---------------------------------------------------------------------------
// Batched 1024x1024 transpose-cast: z selects {Wq,Wk,Wv,Wo}; destinations are
// contiguous in the workspace (wqkv_t then wo_t), so dst = base + z*EMB*EMB.
// Wq folds the 1/8 attention scale.  grid (32, 32, 4), 256 thr.
// ---------------------------------------------------------------------------
__global__ void transpose_cast4(const float* __restrict__ W0, const float* __restrict__ W1,
                                const float* __restrict__ W2, const float* __restrict__ W3,
                                bf16* __restrict__ dst) {
  __shared__ float tile[32][33];
  const int z = blockIdx.z;
  const float* W = (z == 0) ? W0 : (z == 1) ? W1 : (z == 2) ? W2 : W3;
  const float scale = (z == 0) ? 0.125f : 1.0f;
  bf16* Wt = dst + (size_t)z * EMB * EMB;
  const int n0 = blockIdx.x * 32, k0 = blockIdx.y * 32;
  const int tx = threadIdx.x & 31, ty = threadIdx.x >> 5;
#pragma unroll
  for (int i = 0; i < 32; i += 8)
    tile[ty + i][tx] = W[(size_t)(k0 + ty + i) * EMB + n0 + tx];
  __syncthreads();
#pragma unroll
  for (int i = 0; i < 32; i += 8)
    Wt[(size_t)(n0 + ty + i) * EMB + k0 + tx] = (bf16)(tile[tx][ty + i] * scale);
}

// ---------------------------------------------------------------------------
// V transpose: qkv V-part [b*2048+s][2048 + h*64 + d] -> vt[(bh*64+d)*2048+s]
// grid (64 s-tiles, 2 d-tiles, 64 bh), 256 thr, 32x32 tiles.
// ---------------------------------------------------------------------------
__global__ void v_transpose(const bf16* __restrict__ qkv, bf16* __restrict__ vt) {
  __shared__ bf16 tile[32][33];
  const int s0 = blockIdx.x * 32, d0 = blockIdx.y * 32, bh = blockIdx.z;
  const int b = bh >> 4, h = bh & 15;
  const int tx = threadIdx.x & 31, ty = threadIdx.x >> 5;
#pragma unroll
  for (int i = 0; i < 32; i += 8)
    tile[ty + i][tx] = qkv[(size_t)(b * SEQ + s0 + ty + i) * QKVN + 2 * EMB + h * HD + d0 + tx];
  __syncthreads();
#pragma unroll
  for (int i = 0; i < 32; i += 8)
    vt[(size_t)(bh * HD + d0 + ty + i) * SEQ + s0 + tx] = tile[tx][ty + i];
}

// ---------------------------------------------------------------------------
// LayerNorm fp32 -> bf16.  One block (256 thr) per row of 1024.
// ---------------------------------------------------------------------------
__global__ void layernorm_bf16(const float* __restrict__ x, const float* __restrict__ g,
                               const float* __restrict__ b, bf16* __restrict__ out) {
  const int row = blockIdx.x;
  const int t = threadIdx.x;
  const float4 v = ((const float4*)(x + (size_t)row * EMB))[t];
  float s = v.x + v.y + v.z + v.w;
  float ss = v.x * v.x + v.y * v.y + v.z * v.z + v.w * v.w;
#pragma unroll
  for (int off = 32; off; off >>= 1) {
    s += __shfl_down(s, off);
    ss += __shfl_down(ss, off);
  }
  __shared__ float sbuf[8];
  const int wave = t >> 6, lane = t & 63;
  if (lane == 0) { sbuf[wave] = s; sbuf[4 + wave] = ss; }
  __syncthreads();
  if (t == 0) {
    float S = sbuf[0] + sbuf[1] + sbuf[2] + sbuf[3];
    float SS = sbuf[4] + sbuf[5] + sbuf[6] + sbuf[7];
    float mu = S * (1.0f / EMB);
    float var = SS * (1.0f / EMB) - mu * mu;
    sbuf[0] = mu;
    sbuf[1] = rsqrtf(var + 1e-5f);
  }
  __syncthreads();
  const float mu = sbuf[0], rs = sbuf[1];
  const float4 gv = ((const float4*)g)[t];
  const float4 bv = ((const float4*)b)[t];
  bf16x4 o;
  o[0] = (bf16)((v.x - mu) * rs * gv.x + bv.x);
  o[1] = (bf16)((v.y - mu) * rs * gv.y + bv.y);
  o[2] = (bf16)((v.z - mu) * rs * gv.z + bv.z);
  o[3] = (bf16)((v.w - mu) * rs * gv.w + bv.w);
  *(bf16x4*)(out + (size_t)row * EMB + t * 4) = o;
}

// ---------------------------------------------------------------------------
// GEMM: C[M][N] = A[M][K] (bf16 rm) * Bt[N][K]^T (bf16), global_load_lds stage
// 128x128 tile, BK=64, 4 waves.  LDS XOR-swizzled (chunk c of row r at c^(r&7))
// -> 0 measured bank conflicts.  (m97 structure — proven 802 TF on FFN-down;
// LDS-read economy 15.2 B/KFLOP beats the 256-wide 8-phase variants (22.9-38)
// which measured 93 us vs this engine's 85.7 us on the same dispatch.)
// XCD-aware decode: xcd = lin%8 owns m-tiles [xcd*8, xcd*8+8); within an XCD
// the 8 m-tiles cycle fastest (sharing the B panel in that XCD's L2) and the
// per-XCD A slice (2 MB) stays L2-resident across the n sweep.
// Epilogues: 0=bf16  1=+resid f32  2=+bias,GELU(tanh) bf16  3=+bias+resid f32
// ---------------------------------------------------------------------------
template <int EPI, int N_, int K_>
__global__ __launch_bounds__(256, 2) void gemm_bt(
    const bf16* __restrict__ A, const bf16* __restrict__ Bt, void* __restrict__ C,
    const float* __restrict__ bias, const float* __restrict__ resid) {
  constexpr int N = N_, K = K_;
  __shared__ __align__(16) bf16 As[128 * 64];
  __shared__ __align__(16) bf16 Bs[128 * 64];
  const int tid = threadIdx.x;
  const int lane = tid & 63;
  const int wave = tid >> 6;
  const int wm = (wave >> 1) * 64;
  const int wn = (wave & 1) * 64;
  constexpr int tn = N / 128;
  const int lin = blockIdx.y * tn + blockIdx.x;
  const int xcd = lin & 7;             // dispatch round-robin heuristic
  const int idx = lin >> 3;
  const int m0 = (xcd * 8 + (idx & 7)) * 128;   // requires gridDim.y == 64
  const int n0 = (idx >> 3) * 128;
  const int quad = lane >> 4;
  const int l16 = lane & 15;
  const int srow8 = lane >> 3;                   // 0..7
  const int scol = ((lane & 7) ^ srow8) * 8;     // swizzled global col (elems)
  const int xr = l16 & 7;                        // read-side XOR key

  // staging base pointers (lane-fixed); k-advance by +64 elems per iter
  const bf16* ap = A + (size_t)(m0 + wave * 32 + srow8) * K + scol;
  const bf16* bp = Bt + (size_t)(n0 + wave * 32 + srow8) * K + scol;
  bf16* const as0 = &As[wave * 32 * 64];
  bf16* const bs0 = &Bs[wave * 32 * 64];

  f32x4 acc[4][4] = {};

  for (int kt = 0; kt < K; kt += 64) {
    __syncthreads();
#pragma unroll
    for (int q = 0; q < 4; q++) {
      gl2lds16(ap + q * 8 * K, as0 + q * 8 * 64);
      gl2lds16(bp + q * 8 * K, bs0 + q * 8 * 64);
    }
    ap += 64;
    bp += 64;
    __syncthreads();
#pragma unroll
    for (int h = 0; h < 2; h++) {
      const int cp = ((h * 4 + quad) ^ xr) * 8;
      bf16x8 af[4], bfr[4];
#pragma unroll
      for (int i = 0; i < 4; i++)
        af[i] = *(const bf16x8*)&As[(wm + i * 16 + l16) * 64 + cp];
#pragma unroll
      for (int j = 0; j < 4; j++)
        bfr[j] = *(const bf16x8*)&Bs[(wn + j * 16 + l16) * 64 + cp];
#pragma unroll
      for (int i = 0; i < 4; i++)
#pragma unroll
        for (int j = 0; j < 4; j++)
          acc[i][j] = __builtin_amdgcn_mfma_f32_16x16x32_bf16(af[i], bfr[j], acc[i][j], 0, 0, 0);
    }
  }

#pragma unroll
  for (int i = 0; i < 4; i++)
#pragma unroll
    for (int j = 0; j < 4; j++)
#pragma unroll
      for (int r = 0; r < 4; r++) {
        const int row = m0 + wm + i * 16 + quad * 4 + r;
        const int col = n0 + wn + j * 16 + l16;
        const size_t idx2 = (size_t)row * N + col;
        float v = acc[i][j][r];
        if (EPI == 0) {
          ((bf16*)C)[idx2] = (bf16)v;
        } else if (EPI == 1) {
          ((float*)C)[idx2] = v + resid[idx2];
        } else if (EPI == 2) {
          v += bias[col];
          // tanh-form GELU: max |delta| vs exact ~1e-3 << bf16 noise
          const float u = 1.5957691216f * (v + 0.044715f * v * v * v);
          v = v / (1.0f + __expf(-u));
          ((bf16*)C)[idx2] = (bf16)v;
        } else {
          ((float*)C)[idx2] = v + bias[col] + resid[idx2];
        }
      }
}

// ---------------------------------------------------------------------------
// Flash attention (causal), fixed-base softmax.  Q pre-scaled by 1/8.
// Q-tile 64 (4 waves), K-tile 64, q-tile pairing (31-p, p) -> 33 iters/block.
// 1D grid of 1024; decode xcd = bid%8 so all 16 blocks of one (b,h) land on
// one XCD (K/V 512 KB stays in that L2).  K/V staged via global_load_lds with
// XOR-swizzled fetch (chunk c of row r at c^(r&7)) -> conflict-free.
// 6 blocks/CU (LDS 25 KB).
// ---------------------------------------------------------------------------
__global__ __launch_bounds__(256, 6) void flash_attn(
    const bf16* __restrict__ qkv, const bf16* __restrict__ vt, bf16* __restrict__ out) {
  const int bid = blockIdx.x;
  const int xcd = bid & 7;
  const int idx = bid >> 3;            // 0..127
  const int pr = idx & 15;
  const int bh = xcd + ((idx >> 4) << 3);
  const int b = bh >> 4, h = bh & 15;
  const int tid = threadIdx.x;
  const int lane = tid & 63, wave = tid >> 6;
  const int quad = lane >> 4, l16 = lane & 15;

  __shared__ __align__(16) bf16 Ks[64 * 64];
  __shared__ __align__(16) bf16 Vts[64 * 64];   // [d][key]
  __shared__ __align__(16) bf16 Ps[4][16][72];

  const size_t rowbase = (size_t)b * SEQ;
  const int s8 = (lane >> 3) & 7;  // 0..7 staging row within 8-row group
  const int cs = ((lane & 7) ^ s8) * 8;          // swizzled fetch col (elems)
  const int xk = l16 & 7;                        // read-side XOR key
  const bf16* kbase = qkv + rowbase * QKVN + EMB + h * HD;
  const bf16* vbase = vt + (size_t)(bh * HD) * SEQ;

#pragma unroll 1
  for (int half = 0; half < 2; half++) {
    const int qt = half ? pr : 31 - pr;           // heavy tile first
    const int qrow_a = qt * 64 + wave * 16 + l16;
    const bf16* qptr = qkv + (rowbase + qrow_a) * QKVN + h * HD;
    const bf16x8 qf0 = *(const bf16x8*)(qptr + quad * 8);
    const bf16x8 qf1 = *(const bf16x8*)(qptr + 32 + quad * 8);
    f32x4 o0 = {}, o1 = {}, o2 = {}, o3 = {};
    f32x4 lsum = {};
    const int qrow_c = qt * 64 + wave * 16 + quad * 4;

    // staging pointers for this wave (8 rows per gl2lds16 call)
    const bf16* kp = kbase + (size_t)(wave * 8 + s8) * QKVN + cs;
    const bf16* vp = vbase + (size_t)(wave * 8 + s8) * SEQ + cs;

#pragma unroll 1
    for (int kt = 0; kt <= qt; kt++) {
      __syncthreads();
      gl2lds16(kp + (size_t)kt * 64 * QKVN, &Ks[(wave * 8) * 64]);
      gl2lds16(kp + (size_t)(kt * 64 + 32) * QKVN, &Ks[(32 + wave * 8) * 64]);
      gl2lds16(vp + kt * 64, &Vts[(wave * 8) * 64]);
      gl2lds16(vp + (size_t)32 * SEQ + kt * 64, &Vts[(32 + wave * 8) * 64]);
      __syncthreads();

      if (kt < qt) {
        // interior tiles: fully unmasked, no compares, no cross-lane reduce
#pragma unroll
        for (int j = 0; j < 4; j++) {
          const int rr = (j * 16 + l16) * 64;
          const bf16x8 kf0 = *(const bf16x8*)&Ks[rr + (quad ^ xk) * 8];
          const bf16x8 kf1 = *(const bf16x8*)&Ks[rr + ((4 + quad) ^ xk) * 8];
          f32x4 a = {};
          a = __builtin_amdgcn_mfma_f32_16x16x32_bf16(qf0, kf0, a, 0, 0, 0);
          a = __builtin_amdgcn_mfma_f32_16x16x32_bf16(qf1, kf1, a, 0, 0, 0);
#pragma unroll
          for (int r = 0; r < 4; r++) {
            const float pj = __expf(a[r]);
            lsum[r] += pj;
            Ps[wave][quad * 4 + r][j * 16 + l16] = (bf16)pj;
          }
        }
      } else {
        // diagonal tile: j<wave unmasked, j==wave partial mask, j>wave all 0
#pragma unroll
        for (int j = 0; j < 4; j++) {
          if (j > wave) {
#pragma unroll
            for (int r = 0; r < 4; r++)
              Ps[wave][quad * 4 + r][j * 16 + l16] = (bf16)0.0f;
          } else {
            const int rr = (j * 16 + l16) * 64;
            const bf16x8 kf0 = *(const bf16x8*)&Ks[rr + (quad ^ xk) * 8];
            const bf16x8 kf1 = *(const bf16x8*)&Ks[rr + ((4 + quad) ^ xk) * 8];
            f32x4 a = {};
            a = __builtin_amdgcn_mfma_f32_16x16x32_bf16(qf0, kf0, a, 0, 0, 0);
            a = __builtin_amdgcn_mfma_f32_16x16x32_bf16(qf1, kf1, a, 0, 0, 0);
            if (j == wave) {
#pragma unroll
              for (int r = 0; r < 4; r++) {
                const float v = (l16 > quad * 4 + r) ? -INFINITY : a[r];
                const float pj = __expf(v);
                lsum[r] += pj;
                Ps[wave][quad * 4 + r][j * 16 + l16] = (bf16)pj;
              }
            } else {
#pragma unroll
              for (int r = 0; r < 4; r++) {
                const float pj = __expf(a[r]);
                lsum[r] += pj;
                Ps[wave][quad * 4 + r][j * 16 + l16] = (bf16)pj;
              }
            }
          }
        }
      }
      // Ps write->read is same-wave; lgkmcnt ordering suffices (no barrier)

      const bf16x8 af0 = *(const bf16x8*)&Ps[wave][l16][quad * 8];
      const bf16x8 af1 = *(const bf16x8*)&Ps[wave][l16][32 + quad * 8];
#pragma unroll
      for (int j = 0; j < 4; j++) {
        const int rr = (j * 16 + l16) * 64;
        const bf16x8 vf0 = *(const bf16x8*)&Vts[rr + (quad ^ xk) * 8];
        const bf16x8 vf1 = *(const bf16x8*)&Vts[rr + ((4 + quad) ^ xk) * 8];
        f32x4& oj = (j == 0) ? o0 : (j == 1) ? o1 : (j == 2) ? o2 : o3;
        oj = __builtin_amdgcn_mfma_f32_16x16x32_bf16(af0, vf0, oj, 0, 0, 0);
        oj = __builtin_amdgcn_mfma_f32_16x16x32_bf16(af1, vf1, oj, 0, 0, 0);
      }
    }

    // final: reduce l across the 16 columns (lanes of the l16 group), store
#pragma unroll
    for (int r = 0; r < 4; r++) {
      float ls = lsum[r];
      ls += __shfl_xor(ls, 1);
      ls += __shfl_xor(ls, 2);
      ls += __shfl_xor(ls, 4);
      ls += __shfl_xor(ls, 8);
      const float iv = 1.0f / ls;
      bf16* op = out + (rowbase + qrow_c + r) * EMB + h * HD;
      op[0 + l16] = (bf16)(o0[r] * iv);
      op[16 + l16] = (bf16)(o1[r] * iv);
      op[32 + l16] = (bf16)(o2[r] * iv);
      op[48 + l16] = (bf16)(o3[r] * iv);
    }
  }
}

// ---------------------------------------------------------------------------
extern "C" void kernel_launch(void* const* d_in, const int* in_sizes, int n_in,
                              void* d_out, int out_size, void* d_ws, size_t ws_size,
                              hipStream_t stream) {
  const float* x     = (const float*)d_in[0];
  const float* Wq    = (const float*)d_in[1];
  const float* Wk    = (const float*)d_in[2];
  const float* Wv    = (const float*)d_in[3];
  const float* Wo    = (const float*)d_in[4];
  const float* ln1_g = (const float*)d_in[5];
  const float* ln1_b = (const float*)d_in[6];
  const float* ln2_g = (const float*)d_in[7];
  const float* ln2_b = (const float*)d_in[8];
  const float* W1    = (const float*)d_in[9];
  const float* b1    = (const float*)d_in[10];
  const float* W2    = (const float*)d_in[11];
  const float* b2    = (const float*)d_in[12];
  float* out = (float*)d_out;  // doubles as x2 (post-attention residual state)

  bf16* p = (bf16*)d_ws;
  bf16* wqkv_t = p;                 p += (size_t)QKVN * EMB;   // [3072][1024]
  bf16* wo_t   = p;                 p += (size_t)EMB * EMB;    // [1024][1024]
  bf16* w1_t   = p;                 p += (size_t)FFN * EMB;    // [4096][1024]
  bf16* w2_t   = p;                 p += (size_t)EMB * FFN;    // [1024][4096]
  bf16* h      = p;                 p += (size_t)ROWS * EMB;   // LN out; aliased as vt
  bf16* qkv    = p;                 p += (size_t)ROWS * QKVN;  // [8192][3072]
  bf16* attn_o = p;                 p += (size_t)ROWS * EMB;   // [8192][1024]
  bf16* ffn1   = p;                 /* [8192][4096] */
  bf16* vt     = h;  // alias: h (LN1 out) is dead once QKV GEMM completes

  // 1) weight transpose-casts.  Wq/Wk/Wv/Wo in ONE launch (contiguous dests:
  //    wqkv_t then wo_t); Wq folds the 1/8 attention scale.
  transpose_cast4<<<dim3(32, 32, 4), 256, 0, stream>>>(Wq, Wk, Wv, Wo, wqkv_t);
  transpose_cast<<<dim3(128, 32), 256, 0, stream>>>(W1, w1_t, EMB, FFN, 1.0f);
  transpose_cast<<<dim3(32, 128), 256, 0, stream>>>(W2, w2_t, FFN, EMB, 1.0f);

  // 2) LN1
  layernorm_bf16<<<ROWS, 256, 0, stream>>>(x, ln1_g, ln1_b, h);

  // 3) fused QKV projection
  gemm_bt<0, QKVN, EMB><<<dim3(QKVN / 128, ROWS / 128), 256, 0, stream>>>(
      h, wqkv_t, qkv, nullptr, nullptr);

  // 4) V transpose (h is dead now; vt aliases it)
  v_transpose<<<dim3(SEQ / 32, HD / 32, 64), 256, 0, stream>>>(qkv, vt);

  // 5) causal flash attention (1D grid, XCD-aware decode)
  flash_attn<<<1024, 256, 0, stream>>>(qkv, vt, attn_o);

  // 6) output projection + residual -> x2 (in d_out)
  gemm_bt<1, EMB, EMB><<<dim3(EMB / 128, ROWS / 128), 256, 0, stream>>>(
      attn_o, wo_t, out, nullptr, x);

  // 7) LN2 (overwrites vt alias — flash is done)
  layernorm_bf16<<<ROWS, 256, 0, stream>>>(out, ln2_g, ln2_b, h);

  // 8) FFN up + GELU (tanh form)
  gemm_bt<2, FFN, EMB><<<dim3(FFN / 128, ROWS / 128), 256, 0, stream>>>(
      h, w1_t, ffn1, b1, nullptr);

  // 9) FFN down + bias + residual -> final out
  gemm_bt<3, EMB, FFN><<<dim3(EMB / 128, ROWS / 128), 256, 0, stream>>>(
      ffn1, w2_t, out, b2, out);
}